// Round 3
// baseline (427.116 us; speedup 1.0000x reference)
//
#include <hip/hip_runtime.h>
#include <hip/hip_bf16.h>

#define BB 2
#define SS 2048
#define DD 1024
#define HH 16
#define HD 64

typedef __attribute__((ext_vector_type(8))) short bf16x8;
typedef __attribute__((ext_vector_type(4))) float floatx4;

__device__ __forceinline__ short f2bf(float x) {
  __hip_bfloat16 h = __float2bfloat16(x);
  return __builtin_bit_cast(short, h);
}

// pack two fp32 -> two bf16 (RNE) in one instruction
__device__ __forceinline__ unsigned cvtpk_bf16(float lo, float hi) {
  unsigned r;
  asm("v_cvt_pk_bf16_f32 %0, %1, %2" : "=v"(r) : "v"(lo), "v"(hi));
  return r;
}

// async global->LDS, 16B per lane; LDS dest is wave-uniform base + lane*16
__device__ __forceinline__ void load_lds16(const void* g, void* l) {
  __builtin_amdgcn_global_load_lds(
      (const __attribute__((address_space(1))) unsigned int*)g,
      (__attribute__((address_space(3))) unsigned int*)l, 16, 0, 0);
}

__device__ __forceinline__ float redsum16(float v) {
  v += __shfl_xor(v, 1, 64);
  v += __shfl_xor(v, 2, 64);
  v += __shfl_xor(v, 4, 64);
  v += __shfl_xor(v, 8, 64);
  return v;
}

// ---------------------------------------------------------------------------
// prep: fused conv_in (q,k,v fp32->bf16) + conv_w (Wq/Wk/Wv transpose) +
// conv_wo (Wo transpose). 1D grid 13312, block 256.
// ---------------------------------------------------------------------------
__global__ __launch_bounds__(256) void prep(
    const float* __restrict__ q, const float* __restrict__ k,
    const float* __restrict__ v, const float* __restrict__ Wq,
    const float* __restrict__ Wk, const float* __restrict__ Wv,
    const float* __restrict__ Wo, short* __restrict__ qo,
    short* __restrict__ ko, short* __restrict__ vo, short* __restrict__ qT,
    short* __restrict__ kT, short* __restrict__ vT, short* __restrict__ WoT) {
  __shared__ short sT[64 * 72];
  const int blk = blockIdx.x;
  if (blk < 12288) {
    const int which = blk >> 12, x = blk & 4095;
    const float* src = which == 0 ? q : which == 1 ? k : v;
    short* dst       = which == 0 ? qo : which == 1 ? ko : vo;
    size_t i = ((size_t)x * 256 + threadIdx.x) * 4;
    float4 f = *(const float4*)(src + i);
    short4 s;
    s.x = f2bf(f.x); s.y = f2bf(f.y); s.z = f2bf(f.z); s.w = f2bf(f.w);
    *(short4*)(dst + i) = s;
    return;
  }
  const int t = threadIdx.x, r = t >> 2, c0 = (t & 3) * 16;
  const float* src;
  short* dst;
  if (blk < 13056) {  // conv_w: W[h][1024][64] -> WT[h*64+e][1024]
    const int b2 = blk - 12288, which = b2 >> 8, rr = b2 & 255;
    const int dtile = rr & 15, h = rr >> 4, d0 = dtile * 64;
    const float* W = which == 0 ? Wq : which == 1 ? Wk : Wv;
    short* WT      = which == 0 ? qT : which == 1 ? kT : vT;
    src = W + ((size_t)h * DD + d0 + r) * HD + c0;
    dst = WT + ((size_t)h * HD + r) * DD + d0 + c0;
  } else {  // conv_wo: Wo[1024][1024] -> WoT[n][k]
    const int b3 = blk - 13056;
    const int k0 = (b3 & 15) * 64, n0 = (b3 >> 4) * 64;
    src = Wo + (size_t)(k0 + r) * DD + n0 + c0;
    dst = WoT + (size_t)(n0 + r) * DD + k0 + c0;
  }
  const float4* s4 = (const float4*)src;
  float4 f0 = s4[0], f1 = s4[1], f2 = s4[2], f3 = s4[3];
  const float ff[16] = {f0.x, f0.y, f0.z, f0.w, f1.x, f1.y, f1.z, f1.w,
                        f2.x, f2.y, f2.z, f2.w, f3.x, f3.y, f3.z, f3.w};
#pragma unroll
  for (int j = 0; j < 16; ++j) sT[r * 72 + c0 + j] = f2bf(ff[j]);
  __syncthreads();
  alignas(16) short tmp[16];
#pragma unroll
  for (int j = 0; j < 16; ++j) tmp[j] = sT[(c0 + j) * 72 + r];
  *(int4*)(dst) = *(const int4*)(tmp);
  *(int4*)(dst + 8) = *(const int4*)(tmp + 8);
}

// ---------------------------------------------------------------------------
// Projection GEMM: ph = x @ W, M=4096, N=1024, K=1024. q/k: plain [m][n]
// store. Masked rows of q/k are ZEROED here (score = q.k = 0 exactly ->
// exp2(0)=1 in attn, replacing the per-score pad cndmasks), and q is scaled
// by 1/8 * log2(e) so attn can use raw v_exp_f32 (exp2). v: fused transpose
// epilogue -> vhT[bh][e][s]. 1D grid 768, XCD-decoded.
// ---------------------------------------------------------------------------
__global__ __launch_bounds__(256) void proj(
    const short* __restrict__ xq, const short* __restrict__ xk,
    const short* __restrict__ xv, const short* __restrict__ WqT,
    const short* __restrict__ WkT, const short* __restrict__ WvT,
    const int* __restrict__ mask, short* __restrict__ qh,
    short* __restrict__ kh, short* __restrict__ vhT) {
  __shared__ short sA[128 * 32];
  __shared__ short sB[128 * 32];
  __shared__ short sT2[128 * 136];  // v-transpose staging (16B-aligned rows)
  const int xcd = blockIdx.x & 7, tt = blockIdx.x >> 3;
  const int which = tt >> 5;              // 0..2
  const int rest = tt & 31;
  const int j = ((xcd & 3) << 1) | (rest >> 4);   // n-block 0..7
  const int i = ((xcd >> 2) << 4) | (rest & 15);  // m-block 0..31
  const short* X  = which == 0 ? xq : which == 1 ? xk : xv;
  const short* WT = which == 0 ? WqT : which == 1 ? WkT : WvT;
  const int m0 = i * 128, n0 = j * 128;
  const int tid = threadIdx.x, wid = tid >> 6, lane = tid & 63;
  const int quad = lane >> 4, l16 = lane & 15;
  const int wr = wid >> 1, wc = wid & 1;

  floatx4 acc[4][4] = {};
  for (int k0 = 0; k0 < DD; k0 += 32) {
    __syncthreads();
#pragma unroll
    for (int ii = 0; ii < 2; ++ii) {
      const int c = wid * 2 + ii;
      const int ci = c * 64 + lane;
      load_lds16(X + (size_t)(m0 + (ci >> 2)) * DD + k0 + (ci & 3) * 8,
                 &sA[c * 512]);
      load_lds16(WT + (size_t)(n0 + (ci >> 2)) * DD + k0 + (ci & 3) * 8,
                 &sB[c * 512]);
    }
    __syncthreads();
    bf16x8 af[4], bfr[4];
#pragma unroll
    for (int mi = 0; mi < 4; ++mi)
      af[mi] = *(const bf16x8*)&sA[(wr * 64 + mi * 16 + l16) * 32 + quad * 8];
#pragma unroll
    for (int ni = 0; ni < 4; ++ni)
      bfr[ni] = *(const bf16x8*)&sB[(wc * 64 + ni * 16 + l16) * 32 + quad * 8];
#pragma unroll
    for (int mi = 0; mi < 4; ++mi)
#pragma unroll
      for (int ni = 0; ni < 4; ++ni)
        acc[mi][ni] = __builtin_amdgcn_mfma_f32_16x16x32_bf16(
            af[mi], bfr[ni], acc[mi][ni], 0, 0, 0);
  }
  if (which != 2) {
    short* dst = which == 0 ? qh : kh;
    // q: fold 1/sqrt(64) AND log2(e) (attn uses exp2). k: unit scale.
    const float scale = (which == 0) ? 0.18033688f : 1.0f;
#pragma unroll
    for (int mi = 0; mi < 4; ++mi)
#pragma unroll
      for (int r2 = 0; r2 < 4; ++r2) {
        const int m = m0 + wr * 64 + mi * 16 + quad * 4 + r2;
        const float rs = mask[m] ? 0.f : scale;  // zero masked rows
#pragma unroll
        for (int ni = 0; ni < 4; ++ni) {
          const int n = n0 + wc * 64 + ni * 16 + l16;
          dst[(size_t)m * DD + n] = f2bf(acc[mi][ni][r2] * rs);
        }
      }
  } else {
    // v: transpose 128x128 tile through LDS, store vhT[bh][e][s]
    __syncthreads();
#pragma unroll
    for (int mi = 0; mi < 4; ++mi)
#pragma unroll
      for (int ni = 0; ni < 4; ++ni)
#pragma unroll
        for (int r2 = 0; r2 < 4; ++r2) {
          const int ml = wr * 64 + mi * 16 + quad * 4 + r2;  // s-local
          const int nl = wc * 64 + ni * 16 + l16;            // (h,e)-local
          sT2[nl * 136 + ml] = f2bf(acc[mi][ni][r2]);
        }
    __syncthreads();
    const int b = m0 >> 11;
    const int row = tid >> 1, half = tid & 1;  // row = n-local 0..127
    const int h = (n0 + row) >> 6, e = (n0 + row) & 63;
    short* dstp = vhT + ((size_t)(b * HH + h) * HD + e) * SS + (m0 & 2047) +
                  half * 64;
    const short* srcl = &sT2[row * 136 + half * 64];
#pragma unroll
    for (int jj = 0; jj < 8; ++jj)
      *(int4*)(dstp + jj * 8) = *(const int4*)(srcl + jj * 8);
  }
}

// ---------------------------------------------------------------------------
// Flash attention, bf16 MFMA, deferred softmax (t-additive partials).
// Round-2 lesson: 512-block / wave-owns-strip was LATENCY-BOUND (occ 13.7%,
// VALU 13%, MFMA 7%). This round: each strip's t-range splits in 2 halves ->
// 4096 wave-tasks -> 1024 blocks = EXACTLY 4 blocks/CU resident (VGPR<=128
// via launch_bounds(256,4); LDS 20.5KB). 16 waves/CU; critical path 16 tiles.
// Combine = single pair (odd wave dumps, even wave adds+stores), 2 barriers.
// All blocks co-resident -> static placement; per-XCD rank->class map
// interleaves {c, 31-c} so every CU's 4 blocks sum to ~constant work.
// Pad masks pre-folded in proj (zeroed rows -> score 0 -> exp2(0)=1).
// XCD-decoded: bh group {4x..4x+3} on XCD x (K/Vt L2-resident per XCD).
// ---------------------------------------------------------------------------
__global__ __launch_bounds__(256, 4) void attn(
    const short* __restrict__ qh, const short* __restrict__ kh,
    const short* __restrict__ vhT, short* __restrict__ X) {
  __shared__ union {
    short sP[4][32 * 72];   // per-wave P tile (main loop), padded stride 72
    float red[2][40 * 64];  // pair-combine slots (after barrier)
  } u;
  const int tid = threadIdx.x, wid = tid >> 6, lane = tid & 63;
  const int quad = lane >> 4, l16 = lane & 15;
  const int xcd = blockIdx.x & 7, rank = blockIdx.x >> 3;  // 0..127
  const int mmr = rank >> 5, g = rank & 31;
  const int szc = (mmr & 1) ? (31 - g) : g;   // size class; CU slot g gets
  const int nt = 32 - szc;                    // classes {g,31-g,g,31-g}
  const int bh = (xcd << 2) | (((mmr & 1) << 1) | (mmr >> 1));
  const int strip = 2 * nt - 2 + (wid >> 1);  // two same-size strips/block
  const int half = wid & 1;                   // t-range half
  const int b = bh >> 4, h = bh & 15;
  const int row0 = strip * 32;
  const int tstart = half ? (nt >> 1) : 0;
  const int tend = half ? nt : (nt >> 1);

  const short* Q  = qh + (size_t)b * SS * DD + h * HD;
  const short* K  = kh + (size_t)b * SS * DD + h * HD;
  const short* Vt = vhT + (size_t)bh * HD * SS;
  short* sPw = u.sP[wid];

  // Q fragments: A-layout, m = l16 (row row0+mi*16+l16), k = ks*32+quad*8
  bf16x8 aq[2][2];
#pragma unroll
  for (int mi = 0; mi < 2; ++mi)
#pragma unroll
    for (int ks = 0; ks < 2; ++ks)
      aq[mi][ks] = *(const bf16x8*)(Q + (size_t)(row0 + mi * 16 + l16) * DD +
                                    ks * 32 + quad * 8);

  floatx4 o[2][4] = {};
  float lacc[2][4] = {};

  auto step = [&](int tb, bf16x8 (&bkc)[4][2], bf16x8 (&bkn)[4][2]) {
    const int t0 = tb * 64;
    // V loads for this tile issue first: latency hides under QK + softmax
    bf16x8 bv[4][2];
#pragma unroll
    for (int ei = 0; ei < 4; ++ei)
#pragma unroll
      for (int ks = 0; ks < 2; ++ks)
        bv[ei][ks] = *(const bf16x8*)(Vt + (size_t)(ei * 16 + l16) * SS + t0 +
                                      ks * 32 + quad * 8);
    // prefetch next tile's K into the other register buffer
    if (tb + 1 < tend) {
#pragma unroll
      for (int ni = 0; ni < 4; ++ni)
#pragma unroll
        for (int ks = 0; ks < 2; ++ks)
          bkn[ni][ks] =
              *(const bf16x8*)(K + (size_t)(t0 + 64 + ni * 16 + l16) * DD +
                               ks * 32 + quad * 8);
    }
    const bool diag = (tb == nt - 1);  // wave-uniform; only in half 1
#pragma unroll
    for (int mi = 0; mi < 2; ++mi) {
      floatx4 s[4] = {};
#pragma unroll
      for (int ks = 0; ks < 2; ++ks)
#pragma unroll
        for (int ni = 0; ni < 4; ++ni)
          s[ni] = __builtin_amdgcn_mfma_f32_16x16x32_bf16(
              aq[mi][ks], bkc[ni][ks], s[ni], 0, 0, 0);
#pragma unroll
      for (int ni = 0; ni < 4; ++ni)
#pragma unroll
        for (int r2p = 0; r2p < 2; ++r2p) {
          // pads pre-zeroed in proj -> s=0 -> exp2(0)=1 exactly
          float p0 = __builtin_amdgcn_exp2f(s[ni][2 * r2p]);
          float p1 = __builtin_amdgcn_exp2f(s[ni][2 * r2p + 1]);
          if (diag) {  // causal wins over pad
            const int row = row0 + mi * 16 + quad * 4 + 2 * r2p;
            const int col = t0 + ni * 16 + l16;
            if (col > row) p0 = 0.f;
            if (col > row + 1) p1 = 0.f;
          }
          lacc[mi][2 * r2p] += p0;
          lacc[mi][2 * r2p + 1] += p1;
          const unsigned pk = cvtpk_bf16(p0, p1);
          short* wp = &sPw[(mi * 16 + quad * 4 + 2 * r2p) * 72 + ni * 16 + l16];
          wp[0] = (short)pk;           // ds_write_b16
          wp[72] = (short)(pk >> 16);  // ds_write_b16_d16_hi
        }
    }
    // O += P V : P via per-wave LDS round-trip (A-layout)
#pragma unroll
    for (int ks = 0; ks < 2; ++ks) {
      bf16x8 ap[2];
#pragma unroll
      for (int mi = 0; mi < 2; ++mi)
        ap[mi] = *(const bf16x8*)&sPw[(mi * 16 + l16) * 72 + ks * 32 +
                                      quad * 8];
#pragma unroll
      for (int mi = 0; mi < 2; ++mi)
#pragma unroll
        for (int ei = 0; ei < 4; ++ei)
          o[mi][ei] = __builtin_amdgcn_mfma_f32_16x16x32_bf16(
              ap[mi], bv[ei][ks], o[mi][ei], 0, 0, 0);
    }
  };

  if (tstart < tend) {
    bf16x8 bkA[4][2], bkB[4][2];
#pragma unroll
    for (int ni = 0; ni < 4; ++ni)
#pragma unroll
      for (int ks = 0; ks < 2; ++ks)
        bkA[ni][ks] =
            *(const bf16x8*)(K + (size_t)(tstart * 64 + ni * 16 + l16) * DD +
                             ks * 32 + quad * 8);
    int tb = tstart;
    for (;;) {  // 2x unrolled ping-pong over K register buffers
      step(tb, bkA, bkB);
      if (++tb >= tend) break;
      step(tb, bkB, bkA);
      if (++tb >= tend) break;
    }
  }

  // ---- pair combine: half1 dumps, half0 accumulates + epilogue ----
  __syncthreads();  // all waves done with sP; red aliases it
  if (half) {
    float* dst = u.red[wid >> 1];
    int j = 0;
#pragma unroll
    for (int mi = 0; mi < 2; ++mi)
#pragma unroll
      for (int ei = 0; ei < 4; ++ei)
#pragma unroll
        for (int r2 = 0; r2 < 4; ++r2) dst[(j++) * 64 + lane] = o[mi][ei][r2];
#pragma unroll
    for (int mi = 0; mi < 2; ++mi)
#pragma unroll
      for (int r2 = 0; r2 < 4; ++r2) dst[(j++) * 64 + lane] = lacc[mi][r2];
  }
  __syncthreads();
  if (!half) {
    const float* srcp = u.red[wid >> 1];
    int j = 0;
#pragma unroll
    for (int mi = 0; mi < 2; ++mi)
#pragma unroll
      for (int ei = 0; ei < 4; ++ei)
#pragma unroll
        for (int r2 = 0; r2 < 4; ++r2) o[mi][ei][r2] += srcp[(j++) * 64 + lane];
#pragma unroll
    for (int mi = 0; mi < 2; ++mi)
#pragma unroll
      for (int r2 = 0; r2 < 4; ++r2) lacc[mi][r2] += srcp[(j++) * 64 + lane];
#pragma unroll
    for (int mi = 0; mi < 2; ++mi)
#pragma unroll
      for (int r2 = 0; r2 < 4; ++r2) {
        const float inv = 1.0f / redsum16(lacc[mi][r2]);
        const int srow = row0 + mi * 16 + quad * 4 + r2;
#pragma unroll
        for (int ei = 0; ei < 4; ++ei)
          X[((size_t)bh * SS + srow) * HD + ei * 16 + l16] =
              f2bf(o[mi][ei][r2] * inv);
      }
  }
}

// ---------------------------------------------------------------------------
// out = X[4096,1024] @ Wo, via WoT[n][k]. BM=128 BN=64 BK=32, 256 threads.
// grid (32, 16) = 512 blocks (2/CU). fp32 output.
// ---------------------------------------------------------------------------
__global__ __launch_bounds__(256) void oproj(const short* __restrict__ X,
                                             const short* __restrict__ WoT,
                                             float* __restrict__ out) {
  __shared__ short sA[128 * 32];
  __shared__ short sB[64 * 32];
  const int m0 = blockIdx.x * 128, n0 = blockIdx.y * 64;
  const int tid = threadIdx.x, wid = tid >> 6, lane = tid & 63;
  const int quad = lane >> 4, l16 = lane & 15;
  const int wr = wid >> 1, wc = wid & 1;

  floatx4 acc[4][2] = {};
  for (int k0 = 0; k0 < DD; k0 += 32) {
    __syncthreads();
#pragma unroll
    for (int i = 0; i < 2; ++i) {
      const int c = wid * 2 + i;
      const int ci = c * 64 + lane;
      load_lds16(X + (size_t)(m0 + (ci >> 2)) * DD + k0 + (ci & 3) * 8,
                 &sA[c * 512]);
    }
    {
      const int ci = wid * 64 + lane;
      load_lds16(WoT + (size_t)(n0 + (ci >> 2)) * DD + k0 + (ci & 3) * 8,
                 &sB[wid * 512]);
    }
    __syncthreads();
    bf16x8 af[4], bfr[2];
#pragma unroll
    for (int mi = 0; mi < 4; ++mi)
      af[mi] = *(const bf16x8*)&sA[(wr * 64 + mi * 16 + l16) * 32 + quad * 8];
#pragma unroll
    for (int ni = 0; ni < 2; ++ni)
      bfr[ni] = *(const bf16x8*)&sB[(wc * 32 + ni * 16 + l16) * 32 + quad * 8];
#pragma unroll
    for (int mi = 0; mi < 4; ++mi)
#pragma unroll
      for (int ni = 0; ni < 2; ++ni)
        acc[mi][ni] = __builtin_amdgcn_mfma_f32_16x16x32_bf16(
            af[mi], bfr[ni], acc[mi][ni], 0, 0, 0);
  }
#pragma unroll
  for (int mi = 0; mi < 4; ++mi)
#pragma unroll
    for (int ni = 0; ni < 2; ++ni)
#pragma unroll
      for (int r2 = 0; r2 < 4; ++r2)
        out[(size_t)(m0 + wr * 64 + mi * 16 + quad * 4 + r2) * DD + n0 +
            wc * 32 + ni * 16 + l16] = acc[mi][ni][r2];
}

// ---------------------------------------------------------------------------
extern "C" void kernel_launch(void* const* d_in, const int* in_sizes, int n_in,
                              void* d_out, int out_size, void* d_ws,
                              size_t ws_size, hipStream_t stream) {
  const float* q  = (const float*)d_in[0];
  const float* k  = (const float*)d_in[1];
  const float* v  = (const float*)d_in[2];
  const float* Wq = (const float*)d_in[3];
  const float* Wk = (const float*)d_in[4];
  const float* Wv = (const float*)d_in[5];
  const float* Wo = (const float*)d_in[6];
  const int* mask = (const int*)d_in[7];
  float* out = (float*)d_out;

  // workspace layout (shorts); X aliases qb (dead after proj). vhT has its
  // OWN region (kb is still live while proj writes vhT).
  short* ws = (short*)d_ws;
  const size_t NIN = (size_t)BB * SS * DD;  // 4,194,304
  const size_t NWH = (size_t)HH * HD * DD;  // 1,048,576
  short* qb  = ws;        // also X
  short* kb  = ws + NIN;
  short* vb  = ws + 2 * NIN;
  short* WqT = ws + 3 * NIN;
  short* WkT = WqT + NWH;
  short* WvT = WkT + NWH;
  short* WoT = WvT + NWH;
  short* qhp = WoT + (size_t)DD * DD;
  short* khp = qhp + NIN;
  short* vhT = khp + NIN;
  short* Xp  = qb;

  prep<<<dim3(13312), 256, 0, stream>>>(q, k, v, Wq, Wk, Wv, Wo, qb, kb, vb,
                                        WqT, WkT, WvT, WoT);
  proj<<<dim3(768), 256, 0, stream>>>(qb, kb, vb, WqT, WkT, WvT, mask, qhp,
                                      khp, vhT);
  attn<<<dim3(1024), 256, 0, stream>>>(qhp, khp, vhT, Xp);
  oproj<<<dim3(32, 16), 256, 0, stream>>>(Xp, WoT, out);
}

// Round 4
// 277.737 us; speedup vs baseline: 1.5378x; 1.5378x over previous
//
#include <hip/hip_runtime.h>
#include <hip/hip_bf16.h>

#define BB 2
#define SS 2048
#define DD 1024
#define HH 16
#define HD 64

typedef __attribute__((ext_vector_type(8))) short bf16x8;
typedef __attribute__((ext_vector_type(4))) float floatx4;

__device__ __forceinline__ short f2bf(float x) {
  __hip_bfloat16 h = __float2bfloat16(x);
  return __builtin_bit_cast(short, h);
}

// pack two fp32 -> two bf16 (RNE) in one instruction
__device__ __forceinline__ unsigned cvtpk_bf16(float lo, float hi) {
  unsigned r;
  asm("v_cvt_pk_bf16_f32 %0, %1, %2" : "=v"(r) : "v"(lo), "v"(hi));
  return r;
}

// async global->LDS, 16B per lane; LDS dest is wave-uniform base + lane*16
__device__ __forceinline__ void load_lds16(const void* g, void* l) {
  __builtin_amdgcn_global_load_lds(
      (const __attribute__((address_space(1))) unsigned int*)g,
      (__attribute__((address_space(3))) unsigned int*)l, 16, 0, 0);
}

__device__ __forceinline__ float redsum16(float v) {
  v += __shfl_xor(v, 1, 64);
  v += __shfl_xor(v, 2, 64);
  v += __shfl_xor(v, 4, 64);
  v += __shfl_xor(v, 8, 64);
  return v;
}

// ---------------------------------------------------------------------------
// prep: fused conv_in (q,k,v fp32->bf16) + conv_w (Wq/Wk/Wv transpose) +
// conv_wo (Wo transpose). 1D grid 13312, block 256.
// ---------------------------------------------------------------------------
__global__ __launch_bounds__(256) void prep(
    const float* __restrict__ q, const float* __restrict__ k,
    const float* __restrict__ v, const float* __restrict__ Wq,
    const float* __restrict__ Wk, const float* __restrict__ Wv,
    const float* __restrict__ Wo, short* __restrict__ qo,
    short* __restrict__ ko, short* __restrict__ vo, short* __restrict__ qT,
    short* __restrict__ kT, short* __restrict__ vT, short* __restrict__ WoT) {
  __shared__ short sT[64 * 72];
  const int blk = blockIdx.x;
  if (blk < 12288) {
    const int which = blk >> 12, x = blk & 4095;
    const float* src = which == 0 ? q : which == 1 ? k : v;
    short* dst       = which == 0 ? qo : which == 1 ? ko : vo;
    size_t i = ((size_t)x * 256 + threadIdx.x) * 4;
    float4 f = *(const float4*)(src + i);
    short4 s;
    s.x = f2bf(f.x); s.y = f2bf(f.y); s.z = f2bf(f.z); s.w = f2bf(f.w);
    *(short4*)(dst + i) = s;
    return;
  }
  const int t = threadIdx.x, r = t >> 2, c0 = (t & 3) * 16;
  const float* src;
  short* dst;
  if (blk < 13056) {  // conv_w: W[h][1024][64] -> WT[h*64+e][1024]
    const int b2 = blk - 12288, which = b2 >> 8, rr = b2 & 255;
    const int dtile = rr & 15, h = rr >> 4, d0 = dtile * 64;
    const float* W = which == 0 ? Wq : which == 1 ? Wk : Wv;
    short* WT      = which == 0 ? qT : which == 1 ? kT : vT;
    src = W + ((size_t)h * DD + d0 + r) * HD + c0;
    dst = WT + ((size_t)h * HD + r) * DD + d0 + c0;
  } else {  // conv_wo: Wo[1024][1024] -> WoT[n][k]
    const int b3 = blk - 13056;
    const int k0 = (b3 & 15) * 64, n0 = (b3 >> 4) * 64;
    src = Wo + (size_t)(k0 + r) * DD + n0 + c0;
    dst = WoT + (size_t)(n0 + r) * DD + k0 + c0;
  }
  const float4* s4 = (const float4*)src;
  float4 f0 = s4[0], f1 = s4[1], f2 = s4[2], f3 = s4[3];
  const float ff[16] = {f0.x, f0.y, f0.z, f0.w, f1.x, f1.y, f1.z, f1.w,
                        f2.x, f2.y, f2.z, f2.w, f3.x, f3.y, f3.z, f3.w};
#pragma unroll
  for (int j = 0; j < 16; ++j) sT[r * 72 + c0 + j] = f2bf(ff[j]);
  __syncthreads();
  alignas(16) short tmp[16];
#pragma unroll
  for (int j = 0; j < 16; ++j) tmp[j] = sT[(c0 + j) * 72 + r];
  *(int4*)(dst) = *(const int4*)(tmp);
  *(int4*)(dst + 8) = *(const int4*)(tmp + 8);
}

// ---------------------------------------------------------------------------
// Projection GEMM: ph = x @ W, M=4096, N=1024, K=1024. q/k: plain [m][n]
// store. Masked rows of q/k are ZEROED here (score = q.k = 0 exactly ->
// exp2(0)=1 in attn, replacing the per-score pad cndmasks), and q is scaled
// by 1/8 * log2(e) so attn can use raw v_exp_f32 (exp2). v: fused transpose
// epilogue -> vhT[bh][e][s]. 1D grid 768, XCD-decoded.
// ---------------------------------------------------------------------------
__global__ __launch_bounds__(256) void proj(
    const short* __restrict__ xq, const short* __restrict__ xk,
    const short* __restrict__ xv, const short* __restrict__ WqT,
    const short* __restrict__ WkT, const short* __restrict__ WvT,
    const int* __restrict__ mask, short* __restrict__ qh,
    short* __restrict__ kh, short* __restrict__ vhT) {
  __shared__ short sA[128 * 32];
  __shared__ short sB[128 * 32];
  __shared__ short sT2[128 * 136];  // v-transpose staging (16B-aligned rows)
  const int xcd = blockIdx.x & 7, tt = blockIdx.x >> 3;
  const int which = tt >> 5;              // 0..2
  const int rest = tt & 31;
  const int j = ((xcd & 3) << 1) | (rest >> 4);   // n-block 0..7
  const int i = ((xcd >> 2) << 4) | (rest & 15);  // m-block 0..31
  const short* X  = which == 0 ? xq : which == 1 ? xk : xv;
  const short* WT = which == 0 ? WqT : which == 1 ? WkT : WvT;
  const int m0 = i * 128, n0 = j * 128;
  const int tid = threadIdx.x, wid = tid >> 6, lane = tid & 63;
  const int quad = lane >> 4, l16 = lane & 15;
  const int wr = wid >> 1, wc = wid & 1;

  floatx4 acc[4][4] = {};
  for (int k0 = 0; k0 < DD; k0 += 32) {
    __syncthreads();
#pragma unroll
    for (int ii = 0; ii < 2; ++ii) {
      const int c = wid * 2 + ii;
      const int ci = c * 64 + lane;
      load_lds16(X + (size_t)(m0 + (ci >> 2)) * DD + k0 + (ci & 3) * 8,
                 &sA[c * 512]);
      load_lds16(WT + (size_t)(n0 + (ci >> 2)) * DD + k0 + (ci & 3) * 8,
                 &sB[c * 512]);
    }
    __syncthreads();
    bf16x8 af[4], bfr[4];
#pragma unroll
    for (int mi = 0; mi < 4; ++mi)
      af[mi] = *(const bf16x8*)&sA[(wr * 64 + mi * 16 + l16) * 32 + quad * 8];
#pragma unroll
    for (int ni = 0; ni < 4; ++ni)
      bfr[ni] = *(const bf16x8*)&sB[(wc * 64 + ni * 16 + l16) * 32 + quad * 8];
#pragma unroll
    for (int mi = 0; mi < 4; ++mi)
#pragma unroll
      for (int ni = 0; ni < 4; ++ni)
        acc[mi][ni] = __builtin_amdgcn_mfma_f32_16x16x32_bf16(
            af[mi], bfr[ni], acc[mi][ni], 0, 0, 0);
  }
  if (which != 2) {
    short* dst = which == 0 ? qh : kh;
    // q: fold 1/sqrt(64) AND log2(e) (attn uses exp2). k: unit scale.
    const float scale = (which == 0) ? 0.18033688f : 1.0f;
#pragma unroll
    for (int mi = 0; mi < 4; ++mi)
#pragma unroll
      for (int r2 = 0; r2 < 4; ++r2) {
        const int m = m0 + wr * 64 + mi * 16 + quad * 4 + r2;
        const float rs = mask[m] ? 0.f : scale;  // zero masked rows
#pragma unroll
        for (int ni = 0; ni < 4; ++ni) {
          const int n = n0 + wc * 64 + ni * 16 + l16;
          dst[(size_t)m * DD + n] = f2bf(acc[mi][ni][r2] * rs);
        }
      }
  } else {
    // v: transpose 128x128 tile through LDS, store vhT[bh][e][s]
    __syncthreads();
#pragma unroll
    for (int mi = 0; mi < 4; ++mi)
#pragma unroll
      for (int ni = 0; ni < 4; ++ni)
#pragma unroll
        for (int r2 = 0; r2 < 4; ++r2) {
          const int ml = wr * 64 + mi * 16 + quad * 4 + r2;  // s-local
          const int nl = wc * 64 + ni * 16 + l16;            // (h,e)-local
          sT2[nl * 136 + ml] = f2bf(acc[mi][ni][r2]);
        }
    __syncthreads();
    const int b = m0 >> 11;
    const int row = tid >> 1, half = tid & 1;  // row = n-local 0..127
    const int h = (n0 + row) >> 6, e = (n0 + row) & 63;
    short* dstp = vhT + ((size_t)(b * HH + h) * HD + e) * SS + (m0 & 2047) +
                  half * 64;
    const short* srcl = &sT2[row * 136 + half * 64];
#pragma unroll
    for (int jj = 0; jj < 8; ++jj)
      *(int4*)(dstp + jj * 8) = *(const int4*)(srcl + jj * 8);
  }
}

// ---------------------------------------------------------------------------
// Flash attention, bf16 MFMA, deferred softmax (t-additive partials).
// Round-3 lesson: __launch_bounds__(256,4) forced VGPR alloc to 64 ->
// massive scratch spill (FETCH 338MB, WRITE 544MB). THIS round: identical
// structure, bound reverted to (256,2) -> ~124 VGPR (round-2-proven), which
// is <=128 so HW still gives 4 waves/SIMD; grid 1024 = 4 blocks/CU
// co-resident. t-range of each strip split in 2 halves (4096 wave-tasks),
// critical path 16 tiles; pair combine = 2 barriers. Static balance:
// per-XCD rank->class map pairs {c, 31-c} per CU slot.
// Pad masks pre-folded in proj (zeroed rows -> score 0 -> exp2(0)=1).
// XCD-decoded: bh group {4x..4x+3} on XCD x (K/Vt L2-resident per XCD).
// ---------------------------------------------------------------------------
__global__ __launch_bounds__(256, 2) void attn(
    const short* __restrict__ qh, const short* __restrict__ kh,
    const short* __restrict__ vhT, short* __restrict__ X) {
  __shared__ union {
    short sP[4][32 * 72];   // per-wave P tile (main loop), padded stride 72
    float red[2][40 * 64];  // pair-combine slots (after barrier)
  } u;
  const int tid = threadIdx.x, wid = tid >> 6, lane = tid & 63;
  const int quad = lane >> 4, l16 = lane & 15;
  const int xcd = blockIdx.x & 7, rank = blockIdx.x >> 3;  // 0..127
  const int mmr = rank >> 5, g = rank & 31;
  const int szc = (mmr & 1) ? (31 - g) : g;   // size class; CU slot g gets
  const int nt = 32 - szc;                    // classes {g,31-g,g,31-g}
  const int bh = (xcd << 2) | (((mmr & 1) << 1) | (mmr >> 1));
  const int strip = 2 * nt - 2 + (wid >> 1);  // two same-size strips/block
  const int half = wid & 1;                   // t-range half
  const int b = bh >> 4, h = bh & 15;
  const int row0 = strip * 32;
  const int tstart = half ? (nt >> 1) : 0;
  const int tend = half ? nt : (nt >> 1);

  const short* Q  = qh + (size_t)b * SS * DD + h * HD;
  const short* K  = kh + (size_t)b * SS * DD + h * HD;
  const short* Vt = vhT + (size_t)bh * HD * SS;
  short* sPw = u.sP[wid];

  // Q fragments: A-layout, m = l16 (row row0+mi*16+l16), k = ks*32+quad*8
  bf16x8 aq[2][2];
#pragma unroll
  for (int mi = 0; mi < 2; ++mi)
#pragma unroll
    for (int ks = 0; ks < 2; ++ks)
      aq[mi][ks] = *(const bf16x8*)(Q + (size_t)(row0 + mi * 16 + l16) * DD +
                                    ks * 32 + quad * 8);

  floatx4 o[2][4] = {};
  float lacc[2][4] = {};

  auto step = [&](int tb, bf16x8 (&bkc)[4][2], bf16x8 (&bkn)[4][2]) {
    const int t0 = tb * 64;
    // V loads for this tile issue first: latency hides under QK + softmax
    bf16x8 bv[4][2];
#pragma unroll
    for (int ei = 0; ei < 4; ++ei)
#pragma unroll
      for (int ks = 0; ks < 2; ++ks)
        bv[ei][ks] = *(const bf16x8*)(Vt + (size_t)(ei * 16 + l16) * SS + t0 +
                                      ks * 32 + quad * 8);
    // prefetch next tile's K into the other register buffer
    if (tb + 1 < tend) {
#pragma unroll
      for (int ni = 0; ni < 4; ++ni)
#pragma unroll
        for (int ks = 0; ks < 2; ++ks)
          bkn[ni][ks] =
              *(const bf16x8*)(K + (size_t)(t0 + 64 + ni * 16 + l16) * DD +
                               ks * 32 + quad * 8);
    }
    const bool diag = (tb == nt - 1);  // wave-uniform; only in half 1
#pragma unroll
    for (int mi = 0; mi < 2; ++mi) {
      floatx4 s[4] = {};
#pragma unroll
      for (int ks = 0; ks < 2; ++ks)
#pragma unroll
        for (int ni = 0; ni < 4; ++ni)
          s[ni] = __builtin_amdgcn_mfma_f32_16x16x32_bf16(
              aq[mi][ks], bkc[ni][ks], s[ni], 0, 0, 0);
#pragma unroll
      for (int ni = 0; ni < 4; ++ni)
#pragma unroll
        for (int r2p = 0; r2p < 2; ++r2p) {
          // pads pre-zeroed in proj -> s=0 -> exp2(0)=1 exactly
          float p0 = __builtin_amdgcn_exp2f(s[ni][2 * r2p]);
          float p1 = __builtin_amdgcn_exp2f(s[ni][2 * r2p + 1]);
          if (diag) {  // causal wins over pad
            const int row = row0 + mi * 16 + quad * 4 + 2 * r2p;
            const int col = t0 + ni * 16 + l16;
            if (col > row) p0 = 0.f;
            if (col > row + 1) p1 = 0.f;
          }
          lacc[mi][2 * r2p] += p0;
          lacc[mi][2 * r2p + 1] += p1;
          const unsigned pk = cvtpk_bf16(p0, p1);
          short* wp = &sPw[(mi * 16 + quad * 4 + 2 * r2p) * 72 + ni * 16 + l16];
          wp[0] = (short)pk;           // ds_write_b16
          wp[72] = (short)(pk >> 16);  // ds_write_b16_d16_hi
        }
    }
    // O += P V : P via per-wave LDS round-trip (A-layout)
#pragma unroll
    for (int ks = 0; ks < 2; ++ks) {
      bf16x8 ap[2];
#pragma unroll
      for (int mi = 0; mi < 2; ++mi)
        ap[mi] = *(const bf16x8*)&sPw[(mi * 16 + l16) * 72 + ks * 32 +
                                      quad * 8];
#pragma unroll
      for (int mi = 0; mi < 2; ++mi)
#pragma unroll
        for (int ei = 0; ei < 4; ++ei)
          o[mi][ei] = __builtin_amdgcn_mfma_f32_16x16x32_bf16(
              ap[mi], bv[ei][ks], o[mi][ei], 0, 0, 0);
    }
  };

  if (tstart < tend) {
    bf16x8 bkA[4][2], bkB[4][2];
#pragma unroll
    for (int ni = 0; ni < 4; ++ni)
#pragma unroll
      for (int ks = 0; ks < 2; ++ks)
        bkA[ni][ks] =
            *(const bf16x8*)(K + (size_t)(tstart * 64 + ni * 16 + l16) * DD +
                             ks * 32 + quad * 8);
    int tb = tstart;
    for (;;) {  // 2x unrolled ping-pong over K register buffers
      step(tb, bkA, bkB);
      if (++tb >= tend) break;
      step(tb, bkB, bkA);
      if (++tb >= tend) break;
    }
  }

  // ---- pair combine: half1 dumps, half0 accumulates + epilogue ----
  __syncthreads();  // all waves done with sP; red aliases it
  if (half) {
    float* dst = u.red[wid >> 1];
    int j = 0;
#pragma unroll
    for (int mi = 0; mi < 2; ++mi)
#pragma unroll
      for (int ei = 0; ei < 4; ++ei)
#pragma unroll
        for (int r2 = 0; r2 < 4; ++r2) dst[(j++) * 64 + lane] = o[mi][ei][r2];
#pragma unroll
    for (int mi = 0; mi < 2; ++mi)
#pragma unroll
      for (int r2 = 0; r2 < 4; ++r2) dst[(j++) * 64 + lane] = lacc[mi][r2];
  }
  __syncthreads();
  if (!half) {
    const float* srcp = u.red[wid >> 1];
    int j = 0;
#pragma unroll
    for (int mi = 0; mi < 2; ++mi)
#pragma unroll
      for (int ei = 0; ei < 4; ++ei)
#pragma unroll
        for (int r2 = 0; r2 < 4; ++r2) o[mi][ei][r2] += srcp[(j++) * 64 + lane];
#pragma unroll
    for (int mi = 0; mi < 2; ++mi)
#pragma unroll
      for (int r2 = 0; r2 < 4; ++r2) lacc[mi][r2] += srcp[(j++) * 64 + lane];
#pragma unroll
    for (int mi = 0; mi < 2; ++mi)
#pragma unroll
      for (int r2 = 0; r2 < 4; ++r2) {
        const float inv = 1.0f / redsum16(lacc[mi][r2]);
        const int srow = row0 + mi * 16 + quad * 4 + r2;
#pragma unroll
        for (int ei = 0; ei < 4; ++ei)
          X[((size_t)bh * SS + srow) * HD + ei * 16 + l16] =
              f2bf(o[mi][ei][r2] * inv);
      }
  }
}

// ---------------------------------------------------------------------------
// out = X[4096,1024] @ Wo, via WoT[n][k]. BM=128 BN=64 BK=32, 256 threads.
// grid (32, 16) = 512 blocks (2/CU). fp32 output.
// ---------------------------------------------------------------------------
__global__ __launch_bounds__(256) void oproj(const short* __restrict__ X,
                                             const short* __restrict__ WoT,
                                             float* __restrict__ out) {
  __shared__ short sA[128 * 32];
  __shared__ short sB[64 * 32];
  const int m0 = blockIdx.x * 128, n0 = blockIdx.y * 64;
  const int tid = threadIdx.x, wid = tid >> 6, lane = tid & 63;
  const int quad = lane >> 4, l16 = lane & 15;
  const int wr = wid >> 1, wc = wid & 1;

  floatx4 acc[4][2] = {};
  for (int k0 = 0; k0 < DD; k0 += 32) {
    __syncthreads();
#pragma unroll
    for (int i = 0; i < 2; ++i) {
      const int c = wid * 2 + i;
      const int ci = c * 64 + lane;
      load_lds16(X + (size_t)(m0 + (ci >> 2)) * DD + k0 + (ci & 3) * 8,
                 &sA[c * 512]);
    }
    {
      const int ci = wid * 64 + lane;
      load_lds16(WoT + (size_t)(n0 + (ci >> 2)) * DD + k0 + (ci & 3) * 8,
                 &sB[wid * 512]);
    }
    __syncthreads();
    bf16x8 af[4], bfr[2];
#pragma unroll
    for (int mi = 0; mi < 4; ++mi)
      af[mi] = *(const bf16x8*)&sA[(wr * 64 + mi * 16 + l16) * 32 + quad * 8];
#pragma unroll
    for (int ni = 0; ni < 2; ++ni)
      bfr[ni] = *(const bf16x8*)&sB[(wc * 32 + ni * 16 + l16) * 32 + quad * 8];
#pragma unroll
    for (int mi = 0; mi < 4; ++mi)
#pragma unroll
      for (int ni = 0; ni < 2; ++ni)
        acc[mi][ni] = __builtin_amdgcn_mfma_f32_16x16x32_bf16(
            af[mi], bfr[ni], acc[mi][ni], 0, 0, 0);
  }
#pragma unroll
  for (int mi = 0; mi < 4; ++mi)
#pragma unroll
    for (int ni = 0; ni < 2; ++ni)
#pragma unroll
      for (int r2 = 0; r2 < 4; ++r2)
        out[(size_t)(m0 + wr * 64 + mi * 16 + quad * 4 + r2) * DD + n0 +
            wc * 32 + ni * 16 + l16] = acc[mi][ni][r2];
}

// ---------------------------------------------------------------------------
extern "C" void kernel_launch(void* const* d_in, const int* in_sizes, int n_in,
                              void* d_out, int out_size, void* d_ws,
                              size_t ws_size, hipStream_t stream) {
  const float* q  = (const float*)d_in[0];
  const float* k  = (const float*)d_in[1];
  const float* v  = (const float*)d_in[2];
  const float* Wq = (const float*)d_in[3];
  const float* Wk = (const float*)d_in[4];
  const float* Wv = (const float*)d_in[5];
  const float* Wo = (const float*)d_in[6];
  const int* mask = (const int*)d_in[7];
  float* out = (float*)d_out;

  // workspace layout (shorts); X aliases qb (dead after proj). vhT has its
  // OWN region (kb is still live while proj writes vhT).
  short* ws = (short*)d_ws;
  const size_t NIN = (size_t)BB * SS * DD;  // 4,194,304
  const size_t NWH = (size_t)HH * HD * DD;  // 1,048,576
  short* qb  = ws;        // also X
  short* kb  = ws + NIN;
  short* vb  = ws + 2 * NIN;
  short* WqT = ws + 3 * NIN;
  short* WkT = WqT + NWH;
  short* WvT = WkT + NWH;
  short* WoT = WvT + NWH;
  short* qhp = WoT + (size_t)DD * DD;
  short* khp = qhp + NIN;
  short* vhT = khp + NIN;
  short* Xp  = qb;

  prep<<<dim3(13312), 256, 0, stream>>>(q, k, v, Wq, Wk, Wv, Wo, qb, kb, vb,
                                        WqT, WkT, WvT, WoT);
  proj<<<dim3(768), 256, 0, stream>>>(qb, kb, vb, WqT, WkT, WvT, mask, qhp,
                                      khp, vhT);
  attn<<<dim3(1024), 256, 0, stream>>>(qhp, khp, vhT, Xp);
  oproj<<<dim3(32, 16), 256, 0, stream>>>(Xp, WoT, out);
}

// Round 5
// 253.306 us; speedup vs baseline: 1.6862x; 1.0964x over previous
//
#include <hip/hip_runtime.h>
#include <hip/hip_bf16.h>

#define BB 2
#define SS 2048
#define DD 1024
#define HH 16
#define HD 64

typedef __attribute__((ext_vector_type(8))) short bf16x8;
typedef __attribute__((ext_vector_type(4))) float floatx4;

__device__ __forceinline__ short f2bf(float x) {
  __hip_bfloat16 h = __float2bfloat16(x);
  return __builtin_bit_cast(short, h);
}

// pack two fp32 -> two bf16 (RNE) in one instruction
__device__ __forceinline__ unsigned cvtpk_bf16(float lo, float hi) {
  unsigned r;
  asm("v_cvt_pk_bf16_f32 %0, %1, %2" : "=v"(r) : "v"(lo), "v"(hi));
  return r;
}

// async global->LDS, 16B per lane; LDS dest is wave-uniform base + lane*16
__device__ __forceinline__ void load_lds16(const void* g, void* l) {
  __builtin_amdgcn_global_load_lds(
      (const __attribute__((address_space(1))) unsigned int*)g,
      (__attribute__((address_space(3))) unsigned int*)l, 16, 0, 0);
}

__device__ __forceinline__ float redsum16(float v) {
  v += __shfl_xor(v, 1, 64);
  v += __shfl_xor(v, 2, 64);
  v += __shfl_xor(v, 4, 64);
  v += __shfl_xor(v, 8, 64);
  return v;
}

// ---------------------------------------------------------------------------
// prep: fused conv_in (q,k,v fp32->bf16) + conv_w (Wq/Wk/Wv transpose) +
// conv_wo (Wo transpose). 1D grid 13312, block 256.
// ---------------------------------------------------------------------------
__global__ __launch_bounds__(256) void prep(
    const float* __restrict__ q, const float* __restrict__ k,
    const float* __restrict__ v, const float* __restrict__ Wq,
    const float* __restrict__ Wk, const float* __restrict__ Wv,
    const float* __restrict__ Wo, short* __restrict__ qo,
    short* __restrict__ ko, short* __restrict__ vo, short* __restrict__ qT,
    short* __restrict__ kT, short* __restrict__ vT, short* __restrict__ WoT) {
  __shared__ short sT[64 * 72];
  const int blk = blockIdx.x;
  if (blk < 12288) {
    const int which = blk >> 12, x = blk & 4095;
    const float* src = which == 0 ? q : which == 1 ? k : v;
    short* dst       = which == 0 ? qo : which == 1 ? ko : vo;
    size_t i = ((size_t)x * 256 + threadIdx.x) * 4;
    float4 f = *(const float4*)(src + i);
    short4 s;
    s.x = f2bf(f.x); s.y = f2bf(f.y); s.z = f2bf(f.z); s.w = f2bf(f.w);
    *(short4*)(dst + i) = s;
    return;
  }
  const int t = threadIdx.x, r = t >> 2, c0 = (t & 3) * 16;
  const float* src;
  short* dst;
  if (blk < 13056) {  // conv_w: W[h][1024][64] -> WT[h*64+e][1024]
    const int b2 = blk - 12288, which = b2 >> 8, rr = b2 & 255;
    const int dtile = rr & 15, h = rr >> 4, d0 = dtile * 64;
    const float* W = which == 0 ? Wq : which == 1 ? Wk : Wv;
    short* WT      = which == 0 ? qT : which == 1 ? kT : vT;
    src = W + ((size_t)h * DD + d0 + r) * HD + c0;
    dst = WT + ((size_t)h * HD + r) * DD + d0 + c0;
  } else {  // conv_wo: Wo[1024][1024] -> WoT[n][k]
    const int b3 = blk - 13056;
    const int k0 = (b3 & 15) * 64, n0 = (b3 >> 4) * 64;
    src = Wo + (size_t)(k0 + r) * DD + n0 + c0;
    dst = WoT + (size_t)(n0 + r) * DD + k0 + c0;
  }
  const float4* s4 = (const float4*)src;
  float4 f0 = s4[0], f1 = s4[1], f2 = s4[2], f3 = s4[3];
  const float ff[16] = {f0.x, f0.y, f0.z, f0.w, f1.x, f1.y, f1.z, f1.w,
                        f2.x, f2.y, f2.z, f2.w, f3.x, f3.y, f3.z, f3.w};
#pragma unroll
  for (int j = 0; j < 16; ++j) sT[r * 72 + c0 + j] = f2bf(ff[j]);
  __syncthreads();
  alignas(16) short tmp[16];
#pragma unroll
  for (int j = 0; j < 16; ++j) tmp[j] = sT[(c0 + j) * 72 + r];
  *(int4*)(dst) = *(const int4*)(tmp);
  *(int4*)(dst + 8) = *(const int4*)(tmp + 8);
}

// ---------------------------------------------------------------------------
// Projection GEMM: ph = x @ W, M=4096, N=1024, K=1024. q/k: plain [m][n]
// store. Masked rows of q/k are ZEROED here (score = q.k = 0 exactly ->
// exp2(0)=1 in attn, replacing the per-score pad cndmasks), and q is scaled
// by 1/8 * log2(e) so attn can use raw v_exp_f32 (exp2). v: fused transpose
// epilogue -> vhT[bh][e][s]. 1D grid 768, XCD-decoded.
// ---------------------------------------------------------------------------
__global__ __launch_bounds__(256) void proj(
    const short* __restrict__ xq, const short* __restrict__ xk,
    const short* __restrict__ xv, const short* __restrict__ WqT,
    const short* __restrict__ WkT, const short* __restrict__ WvT,
    const int* __restrict__ mask, short* __restrict__ qh,
    short* __restrict__ kh, short* __restrict__ vhT) {
  __shared__ short sA[128 * 32];
  __shared__ short sB[128 * 32];
  __shared__ short sT2[128 * 136];  // v-transpose staging (16B-aligned rows)
  const int xcd = blockIdx.x & 7, tt = blockIdx.x >> 3;
  const int which = tt >> 5;              // 0..2
  const int rest = tt & 31;
  const int j = ((xcd & 3) << 1) | (rest >> 4);   // n-block 0..7
  const int i = ((xcd >> 2) << 4) | (rest & 15);  // m-block 0..31
  const short* X  = which == 0 ? xq : which == 1 ? xk : xv;
  const short* WT = which == 0 ? WqT : which == 1 ? WkT : WvT;
  const int m0 = i * 128, n0 = j * 128;
  const int tid = threadIdx.x, wid = tid >> 6, lane = tid & 63;
  const int quad = lane >> 4, l16 = lane & 15;
  const int wr = wid >> 1, wc = wid & 1;

  floatx4 acc[4][4] = {};
  for (int k0 = 0; k0 < DD; k0 += 32) {
    __syncthreads();
#pragma unroll
    for (int ii = 0; ii < 2; ++ii) {
      const int c = wid * 2 + ii;
      const int ci = c * 64 + lane;
      load_lds16(X + (size_t)(m0 + (ci >> 2)) * DD + k0 + (ci & 3) * 8,
                 &sA[c * 512]);
      load_lds16(WT + (size_t)(n0 + (ci >> 2)) * DD + k0 + (ci & 3) * 8,
                 &sB[c * 512]);
    }
    __syncthreads();
    bf16x8 af[4], bfr[4];
#pragma unroll
    for (int mi = 0; mi < 4; ++mi)
      af[mi] = *(const bf16x8*)&sA[(wr * 64 + mi * 16 + l16) * 32 + quad * 8];
#pragma unroll
    for (int ni = 0; ni < 4; ++ni)
      bfr[ni] = *(const bf16x8*)&sB[(wc * 64 + ni * 16 + l16) * 32 + quad * 8];
#pragma unroll
    for (int mi = 0; mi < 4; ++mi)
#pragma unroll
      for (int ni = 0; ni < 4; ++ni)
        acc[mi][ni] = __builtin_amdgcn_mfma_f32_16x16x32_bf16(
            af[mi], bfr[ni], acc[mi][ni], 0, 0, 0);
  }
  if (which != 2) {
    short* dst = which == 0 ? qh : kh;
    // q: fold 1/sqrt(64) AND log2(e) (attn uses exp2). k: unit scale.
    const float scale = (which == 0) ? 0.18033688f : 1.0f;
#pragma unroll
    for (int mi = 0; mi < 4; ++mi)
#pragma unroll
      for (int r2 = 0; r2 < 4; ++r2) {
        const int m = m0 + wr * 64 + mi * 16 + quad * 4 + r2;
        const float rs = mask[m] ? 0.f : scale;  // zero masked rows
#pragma unroll
        for (int ni = 0; ni < 4; ++ni) {
          const int n = n0 + wc * 64 + ni * 16 + l16;
          dst[(size_t)m * DD + n] = f2bf(acc[mi][ni][r2] * rs);
        }
      }
  } else {
    // v: transpose 128x128 tile through LDS, store vhT[bh][e][s]
    __syncthreads();
#pragma unroll
    for (int mi = 0; mi < 4; ++mi)
#pragma unroll
      for (int ni = 0; ni < 4; ++ni)
#pragma unroll
        for (int r2 = 0; r2 < 4; ++r2) {
          const int ml = wr * 64 + mi * 16 + quad * 4 + r2;  // s-local
          const int nl = wc * 64 + ni * 16 + l16;            // (h,e)-local
          sT2[nl * 136 + ml] = f2bf(acc[mi][ni][r2]);
        }
    __syncthreads();
    const int b = m0 >> 11;
    const int row = tid >> 1, half = tid & 1;  // row = n-local 0..127
    const int h = (n0 + row) >> 6, e = (n0 + row) & 63;
    short* dstp = vhT + ((size_t)(b * HH + h) * HD + e) * SS + (m0 & 2047) +
                  half * 64;
    const short* srcl = &sT2[row * 136 + half * 64];
#pragma unroll
    for (int jj = 0; jj < 8; ++jj)
      *(int4*)(dstp + jj * 8) = *(const int4*)(srcl + jj * 8);
  }
}

// ---------------------------------------------------------------------------
// Flash attention. ROUND-4 LESSON: the 512/1024-block "lean" structures all
// lost to round-0's 2048-block 4-wave t-split (78us) — latency-bound kernels
// need WAVE SUPPLY (8 queued blocks/CU, dynamic refill), not shorter critical
// paths. This round = round-0 structure exactly (2048 blocks, bh/strip
// decode, 4-wave strided t-split, 4-way LDS combine) + the PROVEN diet inner
// loop (pads pre-zeroed in proj -> no mask loads/cndmasks; exp2 w/ folded
// log2e; cvt_pk bf16 pack). No K ping-pong (keeps VGPR ~120 <= 128 -> 4
// waves/SIMD). XCD-decoded: bh group {4x..4x+3} on XCD x (K/Vt L2-resident).
// ---------------------------------------------------------------------------
__global__ __launch_bounds__(256, 2) void attn(
    const short* __restrict__ qh, const short* __restrict__ kh,
    const short* __restrict__ vhT, short* __restrict__ X) {
  __shared__ union {
    short sP[4][32 * 72];   // per-wave P tile (main loop), padded stride 72
    float red[2][40 * 64];  // cross-wave reduction slots (after barrier)
  } u;
  const int tid = threadIdx.x, wid = tid >> 6, lane = tid & 63;
  const int quad = lane >> 4, l16 = lane & 15;
  const int xcd = blockIdx.x & 7, slot = blockIdx.x >> 3;  // 0..255
  const int bh = (xcd << 2) | (slot & 3);
  const int strip = 63 - (slot >> 2);  // heavy strips first per XCD
  const int b = bh >> 4, h = bh & 15;
  const int row0 = strip * 32;

  const short* Q  = qh + (size_t)b * SS * DD + h * HD;
  const short* K  = kh + (size_t)b * SS * DD + h * HD;
  const short* Vt = vhT + (size_t)bh * HD * SS;
  short* sPw = u.sP[wid];

  // Q fragments: A-layout, m = l16 (row row0+mi*16+l16), k = ks*32+quad*8
  bf16x8 aq[2][2];
#pragma unroll
  for (int mi = 0; mi < 2; ++mi)
#pragma unroll
    for (int ks = 0; ks < 2; ++ks)
      aq[mi][ks] = *(const bf16x8*)(Q + (size_t)(row0 + mi * 16 + l16) * DD +
                                    ks * 32 + quad * 8);

  floatx4 o[2][4] = {};
  float lacc[2][4] = {};

  const int ntiles = (row0 >> 6) + 1;  // causal extent in 64-col tiles
  for (int tb = wid; tb < ntiles; tb += 4) {
    const int t0 = tb * 64;
    // Issue ALL of this tile's global loads up front (K then V): V-latency
    // overlaps QK + softmax; compiler waits per first use.
    bf16x8 bk[4][2], bv[4][2];
#pragma unroll
    for (int ni = 0; ni < 4; ++ni)
#pragma unroll
      for (int ks = 0; ks < 2; ++ks)
        bk[ni][ks] = *(const bf16x8*)(K + (size_t)(t0 + ni * 16 + l16) * DD +
                                      ks * 32 + quad * 8);
#pragma unroll
    for (int ei = 0; ei < 4; ++ei)
#pragma unroll
      for (int ks = 0; ks < 2; ++ks)
        bv[ei][ks] = *(const bf16x8*)(Vt + (size_t)(ei * 16 + l16) * SS + t0 +
                                      ks * 32 + quad * 8);
    const bool diag = (tb == ntiles - 1);  // wave-uniform

#pragma unroll
    for (int mi = 0; mi < 2; ++mi) {
      floatx4 s[4] = {};
#pragma unroll
      for (int ks = 0; ks < 2; ++ks)
#pragma unroll
        for (int ni = 0; ni < 4; ++ni)
          s[ni] = __builtin_amdgcn_mfma_f32_16x16x32_bf16(
              aq[mi][ks], bk[ni][ks], s[ni], 0, 0, 0);
#pragma unroll
      for (int ni = 0; ni < 4; ++ni)
#pragma unroll
        for (int r2p = 0; r2p < 2; ++r2p) {
          // pads pre-zeroed in proj -> s=0 -> exp2(0)=1 exactly
          float p0 = __builtin_amdgcn_exp2f(s[ni][2 * r2p]);
          float p1 = __builtin_amdgcn_exp2f(s[ni][2 * r2p + 1]);
          if (diag) {  // causal wins over pad
            const int row = row0 + mi * 16 + quad * 4 + 2 * r2p;
            const int col = t0 + ni * 16 + l16;
            if (col > row) p0 = 0.f;
            if (col > row + 1) p1 = 0.f;
          }
          lacc[mi][2 * r2p] += p0;
          lacc[mi][2 * r2p + 1] += p1;
          const unsigned pk = cvtpk_bf16(p0, p1);
          short* wp = &sPw[(mi * 16 + quad * 4 + 2 * r2p) * 72 + ni * 16 + l16];
          wp[0] = (short)pk;           // ds_write_b16
          wp[72] = (short)(pk >> 16);  // ds_write_b16_d16_hi
        }
    }
    // O += P V : P via per-wave LDS round-trip (A-layout); bv already loaded
#pragma unroll
    for (int ks = 0; ks < 2; ++ks) {
      bf16x8 ap[2];
#pragma unroll
      for (int mi = 0; mi < 2; ++mi)
        ap[mi] = *(const bf16x8*)&sPw[(mi * 16 + l16) * 72 + ks * 32 +
                                      quad * 8];
#pragma unroll
      for (int mi = 0; mi < 2; ++mi)
#pragma unroll
        for (int ei = 0; ei < 4; ++ei)
          o[mi][ei] = __builtin_amdgcn_mfma_f32_16x16x32_bf16(
              ap[mi], bv[ei][ks], o[mi][ei], 0, 0, 0);
    }
  }

  // ---- cross-wave combine: element-major [j][64] slots, pure adds ----
  __syncthreads();  // sP dead from here; red aliases it
  auto dump = [&](float* dst) {
    int j = 0;
#pragma unroll
    for (int mi = 0; mi < 2; ++mi)
#pragma unroll
      for (int ei = 0; ei < 4; ++ei)
#pragma unroll
        for (int r2 = 0; r2 < 4; ++r2) dst[(j++) * 64 + lane] = o[mi][ei][r2];
#pragma unroll
    for (int mi = 0; mi < 2; ++mi)
#pragma unroll
      for (int r2 = 0; r2 < 4; ++r2) dst[(j++) * 64 + lane] = lacc[mi][r2];
  };
  auto accum = [&](const float* srcp) {
    int j = 0;
#pragma unroll
    for (int mi = 0; mi < 2; ++mi)
#pragma unroll
      for (int ei = 0; ei < 4; ++ei)
#pragma unroll
        for (int r2 = 0; r2 < 4; ++r2) o[mi][ei][r2] += srcp[(j++) * 64 + lane];
#pragma unroll
    for (int mi = 0; mi < 2; ++mi)
#pragma unroll
      for (int r2 = 0; r2 < 4; ++r2) lacc[mi][r2] += srcp[(j++) * 64 + lane];
  };
  if (wid == 1) dump(u.red[0]);
  if (wid == 3) dump(u.red[1]);
  __syncthreads();
  if (wid == 0) accum(u.red[0]);
  if (wid == 2) accum(u.red[1]);
  __syncthreads();
  if (wid == 2) dump(u.red[0]);
  __syncthreads();
  if (wid == 0) {
    accum(u.red[0]);
#pragma unroll
    for (int mi = 0; mi < 2; ++mi)
#pragma unroll
      for (int r2 = 0; r2 < 4; ++r2) {
        const float inv = 1.0f / redsum16(lacc[mi][r2]);
        const int srow = row0 + mi * 16 + quad * 4 + r2;
#pragma unroll
        for (int ei = 0; ei < 4; ++ei)
          X[((size_t)bh * SS + srow) * HD + ei * 16 + l16] =
              f2bf(o[mi][ei][r2] * inv);
      }
  }
}

// ---------------------------------------------------------------------------
// out = X[4096,1024] @ Wo, via WoT[n][k]. BM=128 BN=64 BK=32, 256 threads.
// grid (32, 16) = 512 blocks (2/CU). fp32 output.
// ---------------------------------------------------------------------------
__global__ __launch_bounds__(256) void oproj(const short* __restrict__ X,
                                             const short* __restrict__ WoT,
                                             float* __restrict__ out) {
  __shared__ short sA[128 * 32];
  __shared__ short sB[64 * 32];
  const int m0 = blockIdx.x * 128, n0 = blockIdx.y * 64;
  const int tid = threadIdx.x, wid = tid >> 6, lane = tid & 63;
  const int quad = lane >> 4, l16 = lane & 15;
  const int wr = wid >> 1, wc = wid & 1;

  floatx4 acc[4][2] = {};
  for (int k0 = 0; k0 < DD; k0 += 32) {
    __syncthreads();
#pragma unroll
    for (int i = 0; i < 2; ++i) {
      const int c = wid * 2 + i;
      const int ci = c * 64 + lane;
      load_lds16(X + (size_t)(m0 + (ci >> 2)) * DD + k0 + (ci & 3) * 8,
                 &sA[c * 512]);
    }
    {
      const int ci = wid * 64 + lane;
      load_lds16(WoT + (size_t)(n0 + (ci >> 2)) * DD + k0 + (ci & 3) * 8,
                 &sB[wid * 512]);
    }
    __syncthreads();
    bf16x8 af[4], bfr[2];
#pragma unroll
    for (int mi = 0; mi < 4; ++mi)
      af[mi] = *(const bf16x8*)&sA[(wr * 64 + mi * 16 + l16) * 32 + quad * 8];
#pragma unroll
    for (int ni = 0; ni < 2; ++ni)
      bfr[ni] = *(const bf16x8*)&sB[(wc * 32 + ni * 16 + l16) * 32 + quad * 8];
#pragma unroll
    for (int mi = 0; mi < 4; ++mi)
#pragma unroll
      for (int ni = 0; ni < 2; ++ni)
        acc[mi][ni] = __builtin_amdgcn_mfma_f32_16x16x32_bf16(
            af[mi], bfr[ni], acc[mi][ni], 0, 0, 0);
  }
#pragma unroll
  for (int mi = 0; mi < 4; ++mi)
#pragma unroll
    for (int ni = 0; ni < 2; ++ni)
#pragma unroll
      for (int r2 = 0; r2 < 4; ++r2)
        out[(size_t)(m0 + wr * 64 + mi * 16 + quad * 4 + r2) * DD + n0 +
            wc * 32 + ni * 16 + l16] = acc[mi][ni][r2];
}

// ---------------------------------------------------------------------------
extern "C" void kernel_launch(void* const* d_in, const int* in_sizes, int n_in,
                              void* d_out, int out_size, void* d_ws,
                              size_t ws_size, hipStream_t stream) {
  const float* q  = (const float*)d_in[0];
  const float* k  = (const float*)d_in[1];
  const float* v  = (const float*)d_in[2];
  const float* Wq = (const float*)d_in[3];
  const float* Wk = (const float*)d_in[4];
  const float* Wv = (const float*)d_in[5];
  const float* Wo = (const float*)d_in[6];
  const int* mask = (const int*)d_in[7];
  float* out = (float*)d_out;

  // workspace layout (shorts); X aliases qb (dead after proj). vhT has its
  // OWN region (kb is still live while proj writes vhT).
  short* ws = (short*)d_ws;
  const size_t NIN = (size_t)BB * SS * DD;  // 4,194,304
  const size_t NWH = (size_t)HH * HD * DD;  // 1,048,576
  short* qb  = ws;        // also X
  short* kb  = ws + NIN;
  short* vb  = ws + 2 * NIN;
  short* WqT = ws + 3 * NIN;
  short* WkT = WqT + NWH;
  short* WvT = WkT + NWH;
  short* WoT = WvT + NWH;
  short* qhp = WoT + (size_t)DD * DD;
  short* khp = qhp + NIN;
  short* vhT = khp + NIN;
  short* Xp  = qb;

  prep<<<dim3(13312), 256, 0, stream>>>(q, k, v, Wq, Wk, Wv, Wo, qb, kb, vb,
                                        WqT, WkT, WvT, WoT);
  proj<<<dim3(768), 256, 0, stream>>>(qb, kb, vb, WqT, WkT, WvT, mask, qhp,
                                      khp, vhT);
  attn<<<dim3(2048), 256, 0, stream>>>(qhp, khp, vhT, Xp);
  oproj<<<dim3(32, 16), 256, 0, stream>>>(Xp, WoT, out);
}

// Round 6
// 215.761 us; speedup vs baseline: 1.9796x; 1.1740x over previous
//
#include <hip/hip_runtime.h>
#include <hip/hip_bf16.h>

#define BB 2
#define SS 2048
#define DD 1024
#define HH 16
#define HD 64

typedef __attribute__((ext_vector_type(8))) short bf16x8;
typedef __attribute__((ext_vector_type(4))) float floatx4;

__device__ __forceinline__ short f2bf(float x) {
  __hip_bfloat16 h = __float2bfloat16(x);
  return __builtin_bit_cast(short, h);
}

// pack two fp32 -> two bf16 (RNE) in one instruction
__device__ __forceinline__ unsigned cvtpk_bf16(float lo, float hi) {
  unsigned r;
  asm("v_cvt_pk_bf16_f32 %0, %1, %2" : "=v"(r) : "v"(lo), "v"(hi));
  return r;
}

// async global->LDS, 16B per lane; LDS dest is wave-uniform base + lane*16
__device__ __forceinline__ void load_lds16(const void* g, void* l) {
  __builtin_amdgcn_global_load_lds(
      (const __attribute__((address_space(1))) unsigned int*)g,
      (__attribute__((address_space(3))) unsigned int*)l, 16, 0, 0);
}

__device__ __forceinline__ float redsum16(float v) {
  v += __shfl_xor(v, 1, 64);
  v += __shfl_xor(v, 2, 64);
  v += __shfl_xor(v, 4, 64);
  v += __shfl_xor(v, 8, 64);
  return v;
}

// ---------------------------------------------------------------------------
// prep: fused conv_in (q,k,v fp32->bf16) + conv_w (Wq/Wk/Wv transpose) +
// conv_wo (Wo transpose). 1D grid 13312, block 256.
// ---------------------------------------------------------------------------
__global__ __launch_bounds__(256) void prep(
    const float* __restrict__ q, const float* __restrict__ k,
    const float* __restrict__ v, const float* __restrict__ Wq,
    const float* __restrict__ Wk, const float* __restrict__ Wv,
    const float* __restrict__ Wo, short* __restrict__ qo,
    short* __restrict__ ko, short* __restrict__ vo, short* __restrict__ qT,
    short* __restrict__ kT, short* __restrict__ vT, short* __restrict__ WoT) {
  __shared__ short sT[64 * 72];
  const int blk = blockIdx.x;
  if (blk < 12288) {
    const int which = blk >> 12, x = blk & 4095;
    const float* src = which == 0 ? q : which == 1 ? k : v;
    short* dst       = which == 0 ? qo : which == 1 ? ko : vo;
    size_t i = ((size_t)x * 256 + threadIdx.x) * 4;
    float4 f = *(const float4*)(src + i);
    short4 s;
    s.x = f2bf(f.x); s.y = f2bf(f.y); s.z = f2bf(f.z); s.w = f2bf(f.w);
    *(short4*)(dst + i) = s;
    return;
  }
  const int t = threadIdx.x, r = t >> 2, c0 = (t & 3) * 16;
  const float* src;
  short* dst;
  if (blk < 13056) {  // conv_w: W[h][1024][64] -> WT[h*64+e][1024]
    const int b2 = blk - 12288, which = b2 >> 8, rr = b2 & 255;
    const int dtile = rr & 15, h = rr >> 4, d0 = dtile * 64;
    const float* W = which == 0 ? Wq : which == 1 ? Wk : Wv;
    short* WT      = which == 0 ? qT : which == 1 ? kT : vT;
    src = W + ((size_t)h * DD + d0 + r) * HD + c0;
    dst = WT + ((size_t)h * HD + r) * DD + d0 + c0;
  } else {  // conv_wo: Wo[1024][1024] -> WoT[n][k]
    const int b3 = blk - 13056;
    const int k0 = (b3 & 15) * 64, n0 = (b3 >> 4) * 64;
    src = Wo + (size_t)(k0 + r) * DD + n0 + c0;
    dst = WoT + (size_t)(n0 + r) * DD + k0 + c0;
  }
  const float4* s4 = (const float4*)src;
  float4 f0 = s4[0], f1 = s4[1], f2 = s4[2], f3 = s4[3];
  const float ff[16] = {f0.x, f0.y, f0.z, f0.w, f1.x, f1.y, f1.z, f1.w,
                        f2.x, f2.y, f2.z, f2.w, f3.x, f3.y, f3.z, f3.w};
#pragma unroll
  for (int j = 0; j < 16; ++j) sT[r * 72 + c0 + j] = f2bf(ff[j]);
  __syncthreads();
  alignas(16) short tmp[16];
#pragma unroll
  for (int j = 0; j < 16; ++j) tmp[j] = sT[(c0 + j) * 72 + r];
  *(int4*)(dst) = *(const int4*)(tmp);
  *(int4*)(dst + 8) = *(const int4*)(tmp + 8);
}

// ---------------------------------------------------------------------------
// Projection GEMM: ph = x @ W, M=4096, N=1024, K=1024. q/k: plain [m][n]
// store. Masked rows of q/k are ZEROED here (score = q.k = 0 exactly ->
// exp2(0)=1 in attn, replacing the per-score pad cndmasks), and q is scaled
// by 1/8 * log2(e) so attn can use raw v_exp_f32 (exp2). v: fused transpose
// epilogue -> vhT[bh][e][s]. 1D grid 768, XCD-decoded.
// ---------------------------------------------------------------------------
__global__ __launch_bounds__(256) void proj(
    const short* __restrict__ xq, const short* __restrict__ xk,
    const short* __restrict__ xv, const short* __restrict__ WqT,
    const short* __restrict__ WkT, const short* __restrict__ WvT,
    const int* __restrict__ mask, short* __restrict__ qh,
    short* __restrict__ kh, short* __restrict__ vhT) {
  __shared__ short sA[128 * 32];
  __shared__ short sB[128 * 32];
  __shared__ short sT2[128 * 136];  // v-transpose staging (16B-aligned rows)
  const int xcd = blockIdx.x & 7, tt = blockIdx.x >> 3;
  const int which = tt >> 5;              // 0..2
  const int rest = tt & 31;
  const int j = ((xcd & 3) << 1) | (rest >> 4);   // n-block 0..7
  const int i = ((xcd >> 2) << 4) | (rest & 15);  // m-block 0..31
  const short* X  = which == 0 ? xq : which == 1 ? xk : xv;
  const short* WT = which == 0 ? WqT : which == 1 ? WkT : WvT;
  const int m0 = i * 128, n0 = j * 128;
  const int tid = threadIdx.x, wid = tid >> 6, lane = tid & 63;
  const int quad = lane >> 4, l16 = lane & 15;
  const int wr = wid >> 1, wc = wid & 1;

  floatx4 acc[4][4] = {};
  for (int k0 = 0; k0 < DD; k0 += 32) {
    __syncthreads();
#pragma unroll
    for (int ii = 0; ii < 2; ++ii) {
      const int c = wid * 2 + ii;
      const int ci = c * 64 + lane;
      load_lds16(X + (size_t)(m0 + (ci >> 2)) * DD + k0 + (ci & 3) * 8,
                 &sA[c * 512]);
      load_lds16(WT + (size_t)(n0 + (ci >> 2)) * DD + k0 + (ci & 3) * 8,
                 &sB[c * 512]);
    }
    __syncthreads();
    bf16x8 af[4], bfr[4];
#pragma unroll
    for (int mi = 0; mi < 4; ++mi)
      af[mi] = *(const bf16x8*)&sA[(wr * 64 + mi * 16 + l16) * 32 + quad * 8];
#pragma unroll
    for (int ni = 0; ni < 4; ++ni)
      bfr[ni] = *(const bf16x8*)&sB[(wc * 64 + ni * 16 + l16) * 32 + quad * 8];
#pragma unroll
    for (int mi = 0; mi < 4; ++mi)
#pragma unroll
      for (int ni = 0; ni < 4; ++ni)
        acc[mi][ni] = __builtin_amdgcn_mfma_f32_16x16x32_bf16(
            af[mi], bfr[ni], acc[mi][ni], 0, 0, 0);
  }
  if (which != 2) {
    short* dst = which == 0 ? qh : kh;
    // q: fold 1/sqrt(64) AND log2(e) (attn uses exp2). k: unit scale.
    const float scale = (which == 0) ? 0.18033688f : 1.0f;
#pragma unroll
    for (int mi = 0; mi < 4; ++mi)
#pragma unroll
      for (int r2 = 0; r2 < 4; ++r2) {
        const int m = m0 + wr * 64 + mi * 16 + quad * 4 + r2;
        const float rs = mask[m] ? 0.f : scale;  // zero masked rows
#pragma unroll
        for (int ni = 0; ni < 4; ++ni) {
          const int n = n0 + wc * 64 + ni * 16 + l16;
          dst[(size_t)m * DD + n] = f2bf(acc[mi][ni][r2] * rs);
        }
      }
  } else {
    // v: transpose 128x128 tile through LDS, store vhT[bh][e][s]
    __syncthreads();
#pragma unroll
    for (int mi = 0; mi < 4; ++mi)
#pragma unroll
      for (int ni = 0; ni < 4; ++ni)
#pragma unroll
        for (int r2 = 0; r2 < 4; ++r2) {
          const int ml = wr * 64 + mi * 16 + quad * 4 + r2;  // s-local
          const int nl = wc * 64 + ni * 16 + l16;            // (h,e)-local
          sT2[nl * 136 + ml] = f2bf(acc[mi][ni][r2]);
        }
    __syncthreads();
    const int b = m0 >> 11;
    const int row = tid >> 1, half = tid & 1;  // row = n-local 0..127
    const int h = (n0 + row) >> 6, e = (n0 + row) & 63;
    short* dstp = vhT + ((size_t)(b * HH + h) * HD + e) * SS + (m0 & 2047) +
                  half * 64;
    const short* srcl = &sT2[row * 136 + half * 64];
#pragma unroll
    for (int jj = 0; jj < 8; ++jj)
      *(int4*)(dstp + jj * 8) = *(const int4*)(srcl + jj * 8);
  }
}

// ---------------------------------------------------------------------------
// Flash attention, cooperative-LDS version. ROUND-5 LESSON: attn does a
// fixed 17.2 GFLOP of MFMA; at MfmaUtil 9% that IS the 72us. Per-wave K/V
// fragment loads from L2 (16 instr x ~16 txns/tile) + per-tile vmcnt stalls
// were the structure's ceiling. THIS round: block = (bh, 64 q-rows), 4 waves
// x 16 rows each; K-tile + V-tile (64x64 bf16 each) staged ONCE per block
// into double-buffered LDS via global_load_lds, next tile staged BEFORE
// computing current (T3-minimal: one __syncthreads per tile). LDS reads are
// ds_read_b128 at 128B row stride -> G4 XOR swizzle on 16B slots, applied
// BOTH sides (pre-swizzled global source + swizzled read; LDS linear as
// global_load_lds requires). No cross-wave combine (waves own whole rows).
// Diet softmax unchanged (pads pre-zeroed in proj, exp2, cvt_pk).
// 1024 blocks XCD-decoded, heavy-first LPT; LDS 41KB -> 3 blocks/CU.
// ---------------------------------------------------------------------------
__global__ __launch_bounds__(256, 2) void attn(
    const short* __restrict__ qh, const short* __restrict__ kh,
    const short* __restrict__ vhT, short* __restrict__ X) {
  // LDS shorts: [buf0: K 4096 | V 4096][buf1: K 4096 | V 4096][sP 4*1152]
  __shared__ short sm[16384 + 4 * 1152];
  const int tid = threadIdx.x, wid = tid >> 6, lane = tid & 63;
  const int quad = lane >> 4, l16 = lane & 15;
  const int xcd = blockIdx.x & 7, slot = blockIdx.x >> 3;  // 0..127
  const int bh = (xcd << 2) | (slot & 3);
  const int iblk = 31 - (slot >> 2);  // heavy blocks first per XCD
  const int nt = iblk + 1;            // causal extent in 64-col tiles
  const int b = bh >> 4, h = bh & 15;
  const int r0 = iblk * 64;
  const int wrow = r0 + wid * 16;  // this wave's first q-row

  const short* Q  = qh + (size_t)b * SS * DD + h * HD;
  const short* K  = kh + (size_t)b * SS * DD + h * HD;
  const short* Vt = vhT + (size_t)bh * HD * SS;
  short* sPw = &sm[16384 + wid * 1152];  // 16 rows x 72 shorts, per-wave
  const int swz = (l16 & 7) << 3;        // 16B-slot XOR swizzle, in shorts

  // staging geometry: chunk c in 0..511 covers K (row=c>>3, slot=c&7),
  // c in 512..1023 covers V likewise. Source slot pre-swizzled: slot^(row&7).
  const int sr0 = tid >> 3, ss0 = (tid & 7) ^ (sr0 & 7);          // rows 0..31
  const int sr1 = (tid + 256) >> 3, ss1 = (tid & 7) ^ (sr1 & 7);  // rows 32..63
  const short* pK0 = K + (size_t)sr0 * DD + ss0 * 8;
  const short* pK1 = K + (size_t)sr1 * DD + ss1 * 8;
  const short* pV0 = Vt + (size_t)sr0 * SS + ss0 * 8;
  const short* pV1 = Vt + (size_t)sr1 * SS + ss1 * 8;

  auto stage = [&](int buf, int t) {
    const size_t ko = (size_t)t * 64 * DD;
    const int tc = t * 64;
    short* base = &sm[buf * 8192];
    load_lds16(pK0 + ko, base + tid * 8);
    load_lds16(pK1 + ko, base + 2048 + tid * 8);
    load_lds16(pV0 + tc, base + 4096 + tid * 8);
    load_lds16(pV1 + tc, base + 6144 + tid * 8);
  };

  // Q fragments: A-layout, m = l16 (row wrow+l16), k = ks*32+quad*8
  bf16x8 aq[2];
#pragma unroll
  for (int ks = 0; ks < 2; ++ks)
    aq[ks] = *(const bf16x8*)(Q + (size_t)(wrow + l16) * DD + ks * 32 +
                              quad * 8);

  floatx4 o[4] = {};
  float lacc[4] = {};

  stage(0, 0);
  __syncthreads();
  int cur = 0;
  for (int t = 0; t < nt; ++t) {
    if (t + 1 < nt) stage(cur ^ 1, t + 1);  // prefetch next tile (no wait)
    const short* kb = &sm[cur * 8192];
    const short* vb = kb + 4096;
    // QK^T on the staged tile (swizzled reads)
    bf16x8 bk[4][2];
#pragma unroll
    for (int ni = 0; ni < 4; ++ni)
#pragma unroll
      for (int ks = 0; ks < 2; ++ks)
        bk[ni][ks] = *(const bf16x8*)&kb[(ni * 16 + l16) * 64 +
                                         ((ks * 32 + quad * 8) ^ swz)];
    floatx4 s[4] = {};
#pragma unroll
    for (int ks = 0; ks < 2; ++ks)
#pragma unroll
      for (int ni = 0; ni < 4; ++ni)
        s[ni] = __builtin_amdgcn_mfma_f32_16x16x32_bf16(aq[ks], bk[ni][ks],
                                                        s[ni], 0, 0, 0);
    const bool diag = (t == nt - 1);  // block-uniform
    const int t0 = t * 64;
#pragma unroll
    for (int ni = 0; ni < 4; ++ni)
#pragma unroll
      for (int r2p = 0; r2p < 2; ++r2p) {
        // pads pre-zeroed in proj -> s=0 -> exp2(0)=1 exactly
        float p0 = __builtin_amdgcn_exp2f(s[ni][2 * r2p]);
        float p1 = __builtin_amdgcn_exp2f(s[ni][2 * r2p + 1]);
        if (diag) {  // causal wins over pad
          const int row = wrow + quad * 4 + 2 * r2p;
          const int col = t0 + ni * 16 + l16;
          if (col > row) p0 = 0.f;
          if (col > row + 1) p1 = 0.f;
        }
        lacc[2 * r2p] += p0;
        lacc[2 * r2p + 1] += p1;
        const unsigned pk = cvtpk_bf16(p0, p1);
        short* wp = &sPw[(quad * 4 + 2 * r2p) * 72 + ni * 16 + l16];
        wp[0] = (short)pk;           // ds_write_b16
        wp[72] = (short)(pk >> 16);  // ds_write_b16_d16_hi
      }
    // O += P V : P via per-wave LDS round-trip; V from staged tile
#pragma unroll
    for (int ks = 0; ks < 2; ++ks) {
      const bf16x8 ap =
          *(const bf16x8*)&sPw[l16 * 72 + ks * 32 + quad * 8];
#pragma unroll
      for (int ei = 0; ei < 4; ++ei) {
        const bf16x8 bv = *(const bf16x8*)&vb[(ei * 16 + l16) * 64 +
                                              ((ks * 32 + quad * 8) ^ swz)];
        o[ei] = __builtin_amdgcn_mfma_f32_16x16x32_bf16(ap, bv, o[ei], 0, 0,
                                                        0);
      }
    }
    __syncthreads();  // next tile fully staged; all waves done with cur buf
    cur ^= 1;
  }

  // per-wave epilogue: denominator reduce over l16 group, scale, store
#pragma unroll
  for (int r2 = 0; r2 < 4; ++r2) {
    const float inv = 1.0f / redsum16(lacc[r2]);
    const int srow = wrow + quad * 4 + r2;
#pragma unroll
    for (int ei = 0; ei < 4; ++ei)
      X[((size_t)bh * SS + srow) * HD + ei * 16 + l16] =
          f2bf(o[ei][r2] * inv);
  }
}

// ---------------------------------------------------------------------------
// out = X[4096,1024] @ Wo, via WoT[n][k]. BM=128 BN=64 BK=32, 256 threads.
// grid (32, 16) = 512 blocks (2/CU). fp32 output.
// ---------------------------------------------------------------------------
__global__ __launch_bounds__(256) void oproj(const short* __restrict__ X,
                                             const short* __restrict__ WoT,
                                             float* __restrict__ out) {
  __shared__ short sA[128 * 32];
  __shared__ short sB[64 * 32];
  const int m0 = blockIdx.x * 128, n0 = blockIdx.y * 64;
  const int tid = threadIdx.x, wid = tid >> 6, lane = tid & 63;
  const int quad = lane >> 4, l16 = lane & 15;
  const int wr = wid >> 1, wc = wid & 1;

  floatx4 acc[4][2] = {};
  for (int k0 = 0; k0 < DD; k0 += 32) {
    __syncthreads();
#pragma unroll
    for (int i = 0; i < 2; ++i) {
      const int c = wid * 2 + i;
      const int ci = c * 64 + lane;
      load_lds16(X + (size_t)(m0 + (ci >> 2)) * DD + k0 + (ci & 3) * 8,
                 &sA[c * 512]);
    }
    {
      const int ci = wid * 64 + lane;
      load_lds16(WoT + (size_t)(n0 + (ci >> 2)) * DD + k0 + (ci & 3) * 8,
                 &sB[wid * 512]);
    }
    __syncthreads();
    bf16x8 af[4], bfr[2];
#pragma unroll
    for (int mi = 0; mi < 4; ++mi)
      af[mi] = *(const bf16x8*)&sA[(wr * 64 + mi * 16 + l16) * 32 + quad * 8];
#pragma unroll
    for (int ni = 0; ni < 2; ++ni)
      bfr[ni] = *(const bf16x8*)&sB[(wc * 32 + ni * 16 + l16) * 32 + quad * 8];
#pragma unroll
    for (int mi = 0; mi < 4; ++mi)
#pragma unroll
      for (int ni = 0; ni < 2; ++ni)
        acc[mi][ni] = __builtin_amdgcn_mfma_f32_16x16x32_bf16(
            af[mi], bfr[ni], acc[mi][ni], 0, 0, 0);
  }
#pragma unroll
  for (int mi = 0; mi < 4; ++mi)
#pragma unroll
    for (int ni = 0; ni < 2; ++ni)
#pragma unroll
      for (int r2 = 0; r2 < 4; ++r2)
        out[(size_t)(m0 + wr * 64 + mi * 16 + quad * 4 + r2) * DD + n0 +
            wc * 32 + ni * 16 + l16] = acc[mi][ni][r2];
}

// ---------------------------------------------------------------------------
extern "C" void kernel_launch(void* const* d_in, const int* in_sizes, int n_in,
                              void* d_out, int out_size, void* d_ws,
                              size_t ws_size, hipStream_t stream) {
  const float* q  = (const float*)d_in[0];
  const float* k  = (const float*)d_in[1];
  const float* v  = (const float*)d_in[2];
  const float* Wq = (const float*)d_in[3];
  const float* Wk = (const float*)d_in[4];
  const float* Wv = (const float*)d_in[5];
  const float* Wo = (const float*)d_in[6];
  const int* mask = (const int*)d_in[7];
  float* out = (float*)d_out;

  // workspace layout (shorts); X aliases qb (dead after proj). vhT has its
  // OWN region (kb is still live while proj writes vhT).
  short* ws = (short*)d_ws;
  const size_t NIN = (size_t)BB * SS * DD;  // 4,194,304
  const size_t NWH = (size_t)HH * HD * DD;  // 1,048,576
  short* qb  = ws;        // also X
  short* kb  = ws + NIN;
  short* vb  = ws + 2 * NIN;
  short* WqT = ws + 3 * NIN;
  short* WkT = WqT + NWH;
  short* WvT = WkT + NWH;
  short* WoT = WvT + NWH;
  short* qhp = WoT + (size_t)DD * DD;
  short* khp = qhp + NIN;
  short* vhT = khp + NIN;
  short* Xp  = qb;

  prep<<<dim3(13312), 256, 0, stream>>>(q, k, v, Wq, Wk, Wv, Wo, qb, kb, vb,
                                        WqT, WkT, WvT, WoT);
  proj<<<dim3(768), 256, 0, stream>>>(qb, kb, vb, WqT, WkT, WvT, mask, qhp,
                                      khp, vhT);
  attn<<<dim3(1024), 256, 0, stream>>>(qhp, khp, vhT, Xp);
  oproj<<<dim3(32, 16), 256, 0, stream>>>(Xp, WoT, out);
}

// Round 7
// 211.755 us; speedup vs baseline: 2.0170x; 1.0189x over previous
//
#include <hip/hip_runtime.h>
#include <hip/hip_bf16.h>

#define BB 2
#define SS 2048
#define DD 1024
#define HH 16
#define HD 64

typedef __attribute__((ext_vector_type(8))) short bf16x8;
typedef __attribute__((ext_vector_type(4))) float floatx4;

__device__ __forceinline__ short f2bf(float x) {
  __hip_bfloat16 h = __float2bfloat16(x);
  return __builtin_bit_cast(short, h);
}

// pack two fp32 -> two bf16 (RNE) in one instruction
__device__ __forceinline__ unsigned cvtpk_bf16(float lo, float hi) {
  unsigned r;
  asm("v_cvt_pk_bf16_f32 %0, %1, %2" : "=v"(r) : "v"(lo), "v"(hi));
  return r;
}

// async global->LDS, 16B per lane; LDS dest is wave-uniform base + lane*16
__device__ __forceinline__ void load_lds16(const void* g, void* l) {
  __builtin_amdgcn_global_load_lds(
      (const __attribute__((address_space(1))) unsigned int*)g,
      (__attribute__((address_space(3))) unsigned int*)l, 16, 0, 0);
}

__device__ __forceinline__ float redsum16(float v) {
  v += __shfl_xor(v, 1, 64);
  v += __shfl_xor(v, 2, 64);
  v += __shfl_xor(v, 4, 64);
  v += __shfl_xor(v, 8, 64);
  return v;
}

// ---------------------------------------------------------------------------
// prep: fused conv_in (q,k,v fp32->bf16) + conv_w (Wq/Wk/Wv transpose) +
// conv_wo (Wo transpose). 1D grid 13312, block 256.
// ---------------------------------------------------------------------------
__global__ __launch_bounds__(256) void prep(
    const float* __restrict__ q, const float* __restrict__ k,
    const float* __restrict__ v, const float* __restrict__ Wq,
    const float* __restrict__ Wk, const float* __restrict__ Wv,
    const float* __restrict__ Wo, short* __restrict__ qo,
    short* __restrict__ ko, short* __restrict__ vo, short* __restrict__ qT,
    short* __restrict__ kT, short* __restrict__ vT, short* __restrict__ WoT) {
  __shared__ short sT[64 * 72];
  const int blk = blockIdx.x;
  if (blk < 12288) {
    const int which = blk >> 12, x = blk & 4095;
    const float* src = which == 0 ? q : which == 1 ? k : v;
    short* dst       = which == 0 ? qo : which == 1 ? ko : vo;
    size_t i = ((size_t)x * 256 + threadIdx.x) * 4;
    float4 f = *(const float4*)(src + i);
    short4 s;
    s.x = f2bf(f.x); s.y = f2bf(f.y); s.z = f2bf(f.z); s.w = f2bf(f.w);
    *(short4*)(dst + i) = s;
    return;
  }
  const int t = threadIdx.x, r = t >> 2, c0 = (t & 3) * 16;
  const float* src;
  short* dst;
  if (blk < 13056) {  // conv_w: W[h][1024][64] -> WT[h*64+e][1024]
    const int b2 = blk - 12288, which = b2 >> 8, rr = b2 & 255;
    const int dtile = rr & 15, h = rr >> 4, d0 = dtile * 64;
    const float* W = which == 0 ? Wq : which == 1 ? Wk : Wv;
    short* WT      = which == 0 ? qT : which == 1 ? kT : vT;
    src = W + ((size_t)h * DD + d0 + r) * HD + c0;
    dst = WT + ((size_t)h * HD + r) * DD + d0 + c0;
  } else {  // conv_wo: Wo[1024][1024] -> WoT[n][k]
    const int b3 = blk - 13056;
    const int k0 = (b3 & 15) * 64, n0 = (b3 >> 4) * 64;
    src = Wo + (size_t)(k0 + r) * DD + n0 + c0;
    dst = WoT + (size_t)(n0 + r) * DD + k0 + c0;
  }
  const float4* s4 = (const float4*)src;
  float4 f0 = s4[0], f1 = s4[1], f2 = s4[2], f3 = s4[3];
  const float ff[16] = {f0.x, f0.y, f0.z, f0.w, f1.x, f1.y, f1.z, f1.w,
                        f2.x, f2.y, f2.z, f2.w, f3.x, f3.y, f3.z, f3.w};
#pragma unroll
  for (int j = 0; j < 16; ++j) sT[r * 72 + c0 + j] = f2bf(ff[j]);
  __syncthreads();
  alignas(16) short tmp[16];
#pragma unroll
  for (int j = 0; j < 16; ++j) tmp[j] = sT[(c0 + j) * 72 + r];
  *(int4*)(dst) = *(const int4*)(tmp);
  *(int4*)(dst + 8) = *(const int4*)(tmp + 8);
}

// ---------------------------------------------------------------------------
// Projection GEMM: ph = x @ W, M=4096, N=1024, K=1024. ROUND-7: K-loop LDS
// staging is DOUBLE-BUFFERED (stage k+1 issued before computing k, one
// barrier/iter — the round-6 attn pattern; was: stage -> vmcnt(0)-drain ->
// tiny compute, 32x serial latency). The 34.8KB v-transpose buffer now
// ALIASES the staging buffers (dead after the K-loop), processed in two
// 64-row halves: LDS 51.2 -> 32.8KB => 4 blocks/CU (was 3).
// q/k: masked rows ZEROED (score = 0 -> exp2(0)=1 in attn), q scaled by
// 1/8*log2(e). v: fused transpose -> vhT[bh][e][s]. Grid 768, XCD-decoded.
// ---------------------------------------------------------------------------
__global__ __launch_bounds__(256) void proj(
    const short* __restrict__ xq, const short* __restrict__ xk,
    const short* __restrict__ xv, const short* __restrict__ WqT,
    const short* __restrict__ WkT, const short* __restrict__ WvT,
    const int* __restrict__ mask, short* __restrict__ qh,
    short* __restrict__ kh, short* __restrict__ vhT) {
  __shared__ union {
    struct {
      short A[2][128 * 32];  // K-loop staging, double-buffered
      short B[2][128 * 32];
    } s;
    short tr[64 * 136];  // v-transpose half-tile staging (aliases, post-loop)
  } u;
  const int xcd = blockIdx.x & 7, tt = blockIdx.x >> 3;
  const int which = tt >> 5;              // 0..2
  const int rest = tt & 31;
  const int j = ((xcd & 3) << 1) | (rest >> 4);   // n-block 0..7
  const int i = ((xcd >> 2) << 4) | (rest & 15);  // m-block 0..31
  const short* X  = which == 0 ? xq : which == 1 ? xk : xv;
  const short* WT = which == 0 ? WqT : which == 1 ? WkT : WvT;
  const int m0 = i * 128, n0 = j * 128;
  const int tid = threadIdx.x, wid = tid >> 6, lane = tid & 63;
  const int quad = lane >> 4, l16 = lane & 15;
  const int wr = wid >> 1, wc = wid & 1;

  auto stage = [&](int buf, int k0) {
#pragma unroll
    for (int ii = 0; ii < 2; ++ii) {
      const int c = wid * 2 + ii;
      const int ci = c * 64 + lane;
      load_lds16(X + (size_t)(m0 + (ci >> 2)) * DD + k0 + (ci & 3) * 8,
                 &u.s.A[buf][c * 512]);
      load_lds16(WT + (size_t)(n0 + (ci >> 2)) * DD + k0 + (ci & 3) * 8,
                 &u.s.B[buf][c * 512]);
    }
  };

  floatx4 acc[4][4] = {};
  stage(0, 0);
  __syncthreads();
  int cur = 0;
  for (int k0 = 0; k0 < DD; k0 += 32) {
    if (k0 + 32 < DD) stage(cur ^ 1, k0 + 32);  // prefetch next K-step
    bf16x8 af[4], bfr[4];
#pragma unroll
    for (int mi = 0; mi < 4; ++mi)
      af[mi] =
          *(const bf16x8*)&u.s.A[cur][(wr * 64 + mi * 16 + l16) * 32 +
                                      quad * 8];
#pragma unroll
    for (int ni = 0; ni < 4; ++ni)
      bfr[ni] =
          *(const bf16x8*)&u.s.B[cur][(wc * 64 + ni * 16 + l16) * 32 +
                                      quad * 8];
#pragma unroll
    for (int mi = 0; mi < 4; ++mi)
#pragma unroll
      for (int ni = 0; ni < 4; ++ni)
        acc[mi][ni] = __builtin_amdgcn_mfma_f32_16x16x32_bf16(
            af[mi], bfr[ni], acc[mi][ni], 0, 0, 0);
    __syncthreads();  // next buffer staged; all waves done with cur
    cur ^= 1;
  }

  if (which != 2) {
    short* dst = which == 0 ? qh : kh;
    // q: fold 1/sqrt(64) AND log2(e) (attn uses exp2). k: unit scale.
    const float scale = (which == 0) ? 0.18033688f : 1.0f;
#pragma unroll
    for (int mi = 0; mi < 4; ++mi)
#pragma unroll
      for (int r2 = 0; r2 < 4; ++r2) {
        const int m = m0 + wr * 64 + mi * 16 + quad * 4 + r2;
        const float rs = mask[m] ? 0.f : scale;  // zero masked rows
#pragma unroll
        for (int ni = 0; ni < 4; ++ni) {
          const int n = n0 + wc * 64 + ni * 16 + l16;
          dst[(size_t)m * DD + n] = f2bf(acc[mi][ni][r2] * rs);
        }
      }
  } else {
    // v: transpose 128x128 tile -> vhT[bh][e][s], two 64-row halves through
    // u.tr (aliases the staging buffers; K-loop's final barrier precedes us)
    const int b = m0 >> 11;
#pragma unroll
    for (int p = 0; p < 2; ++p) {
      if (wc == p) {  // waves holding nl in [p*64, p*64+64)
#pragma unroll
        for (int mi = 0; mi < 4; ++mi)
#pragma unroll
          for (int ni = 0; ni < 4; ++ni)
#pragma unroll
            for (int r2 = 0; r2 < 4; ++r2) {
              const int ml = wr * 64 + mi * 16 + quad * 4 + r2;  // s-local
              const int nl = ni * 16 + l16;  // (h,e)-local within half
              u.tr[nl * 136 + ml] = f2bf(acc[mi][ni][r2]);
            }
      }
      __syncthreads();
      const int row = tid >> 2, part = tid & 3;  // row 0..63, 32-short parts
      const int gn = n0 + p * 64 + row;
      const int h = gn >> 6, e = gn & 63;
      short* dstp = vhT + ((size_t)(b * HH + h) * HD + e) * SS + (m0 & 2047) +
                    part * 32;
      const short* srcl = &u.tr[row * 136 + part * 32];
#pragma unroll
      for (int jj = 0; jj < 4; ++jj)
        *(int4*)(dstp + jj * 8) = *(const int4*)(srcl + jj * 8);
      if (p == 0) __syncthreads();
    }
  }
}

// ---------------------------------------------------------------------------
// Flash attention, cooperative-LDS version (round-6, unchanged — 72->~35us).
// block = (bh, 64 q-rows), 4 waves x 16 rows; K/V tiles (64x64 bf16) staged
// into double-buffered LDS via global_load_lds, next tile staged BEFORE
// computing current; one __syncthreads per tile. G4 XOR swizzle on 16B slots
// applied both sides (pre-swizzled global source + swizzled read). No
// cross-wave combine. Diet softmax (pads pre-zeroed in proj, exp2, cvt_pk).
// 1024 blocks XCD-decoded, heavy-first.
// ---------------------------------------------------------------------------
__global__ __launch_bounds__(256, 2) void attn(
    const short* __restrict__ qh, const short* __restrict__ kh,
    const short* __restrict__ vhT, short* __restrict__ X) {
  // LDS shorts: [buf0: K 4096 | V 4096][buf1: K 4096 | V 4096][sP 4*1152]
  __shared__ short sm[16384 + 4 * 1152];
  const int tid = threadIdx.x, wid = tid >> 6, lane = tid & 63;
  const int quad = lane >> 4, l16 = lane & 15;
  const int xcd = blockIdx.x & 7, slot = blockIdx.x >> 3;  // 0..127
  const int bh = (xcd << 2) | (slot & 3);
  const int iblk = 31 - (slot >> 2);  // heavy blocks first per XCD
  const int nt = iblk + 1;            // causal extent in 64-col tiles
  const int b = bh >> 4, h = bh & 15;
  const int r0 = iblk * 64;
  const int wrow = r0 + wid * 16;  // this wave's first q-row

  const short* Q  = qh + (size_t)b * SS * DD + h * HD;
  const short* K  = kh + (size_t)b * SS * DD + h * HD;
  const short* Vt = vhT + (size_t)bh * HD * SS;
  short* sPw = &sm[16384 + wid * 1152];  // 16 rows x 72 shorts, per-wave
  const int swz = (l16 & 7) << 3;        // 16B-slot XOR swizzle, in shorts

  // staging geometry: chunk c in 0..511 covers K (row=c>>3, slot=c&7),
  // c in 512..1023 covers V likewise. Source slot pre-swizzled: slot^(row&7).
  const int sr0 = tid >> 3, ss0 = (tid & 7) ^ (sr0 & 7);          // rows 0..31
  const int sr1 = (tid + 256) >> 3, ss1 = (tid & 7) ^ (sr1 & 7);  // rows 32..63
  const short* pK0 = K + (size_t)sr0 * DD + ss0 * 8;
  const short* pK1 = K + (size_t)sr1 * DD + ss1 * 8;
  const short* pV0 = Vt + (size_t)sr0 * SS + ss0 * 8;
  const short* pV1 = Vt + (size_t)sr1 * SS + ss1 * 8;

  auto stage = [&](int buf, int t) {
    const size_t ko = (size_t)t * 64 * DD;
    const int tc = t * 64;
    short* base = &sm[buf * 8192];
    load_lds16(pK0 + ko, base + tid * 8);
    load_lds16(pK1 + ko, base + 2048 + tid * 8);
    load_lds16(pV0 + tc, base + 4096 + tid * 8);
    load_lds16(pV1 + tc, base + 6144 + tid * 8);
  };

  // Q fragments: A-layout, m = l16 (row wrow+l16), k = ks*32+quad*8
  bf16x8 aq[2];
#pragma unroll
  for (int ks = 0; ks < 2; ++ks)
    aq[ks] = *(const bf16x8*)(Q + (size_t)(wrow + l16) * DD + ks * 32 +
                              quad * 8);

  floatx4 o[4] = {};
  float lacc[4] = {};

  stage(0, 0);
  __syncthreads();
  int cur = 0;
  for (int t = 0; t < nt; ++t) {
    if (t + 1 < nt) stage(cur ^ 1, t + 1);  // prefetch next tile (no wait)
    const short* kb = &sm[cur * 8192];
    const short* vb = kb + 4096;
    // QK^T on the staged tile (swizzled reads)
    bf16x8 bk[4][2];
#pragma unroll
    for (int ni = 0; ni < 4; ++ni)
#pragma unroll
      for (int ks = 0; ks < 2; ++ks)
        bk[ni][ks] = *(const bf16x8*)&kb[(ni * 16 + l16) * 64 +
                                         ((ks * 32 + quad * 8) ^ swz)];
    floatx4 s[4] = {};
#pragma unroll
    for (int ks = 0; ks < 2; ++ks)
#pragma unroll
      for (int ni = 0; ni < 4; ++ni)
        s[ni] = __builtin_amdgcn_mfma_f32_16x16x32_bf16(aq[ks], bk[ni][ks],
                                                        s[ni], 0, 0, 0);
    const bool diag = (t == nt - 1);  // block-uniform
    const int t0 = t * 64;
#pragma unroll
    for (int ni = 0; ni < 4; ++ni)
#pragma unroll
      for (int r2p = 0; r2p < 2; ++r2p) {
        // pads pre-zeroed in proj -> s=0 -> exp2(0)=1 exactly
        float p0 = __builtin_amdgcn_exp2f(s[ni][2 * r2p]);
        float p1 = __builtin_amdgcn_exp2f(s[ni][2 * r2p + 1]);
        if (diag) {  // causal wins over pad
          const int row = wrow + quad * 4 + 2 * r2p;
          const int col = t0 + ni * 16 + l16;
          if (col > row) p0 = 0.f;
          if (col > row + 1) p1 = 0.f;
        }
        lacc[2 * r2p] += p0;
        lacc[2 * r2p + 1] += p1;
        const unsigned pk = cvtpk_bf16(p0, p1);
        short* wp = &sPw[(quad * 4 + 2 * r2p) * 72 + ni * 16 + l16];
        wp[0] = (short)pk;           // ds_write_b16
        wp[72] = (short)(pk >> 16);  // ds_write_b16_d16_hi
      }
    // O += P V : P via per-wave LDS round-trip; V from staged tile
#pragma unroll
    for (int ks = 0; ks < 2; ++ks) {
      const bf16x8 ap =
          *(const bf16x8*)&sPw[l16 * 72 + ks * 32 + quad * 8];
#pragma unroll
      for (int ei = 0; ei < 4; ++ei) {
        const bf16x8 bv = *(const bf16x8*)&vb[(ei * 16 + l16) * 64 +
                                              ((ks * 32 + quad * 8) ^ swz)];
        o[ei] = __builtin_amdgcn_mfma_f32_16x16x32_bf16(ap, bv, o[ei], 0, 0,
                                                        0);
      }
    }
    __syncthreads();  // next tile fully staged; all waves done with cur buf
    cur ^= 1;
  }

  // per-wave epilogue: denominator reduce over l16 group, scale, store
#pragma unroll
  for (int r2 = 0; r2 < 4; ++r2) {
    const float inv = 1.0f / redsum16(lacc[r2]);
    const int srow = wrow + quad * 4 + r2;
#pragma unroll
    for (int ei = 0; ei < 4; ++ei)
      X[((size_t)bh * SS + srow) * HD + ei * 16 + l16] =
          f2bf(o[ei][r2] * inv);
  }
}

// ---------------------------------------------------------------------------
// out = X[4096,1024] @ Wo, via WoT[n][k]. BM=128 BN=64 BK=32, 256 threads.
// grid (32, 16) = 512 blocks (2/CU). fp32 output. ROUND-7: double-buffered
// LDS staging (same pattern as proj/attn), one barrier per K-step.
// ---------------------------------------------------------------------------
__global__ __launch_bounds__(256) void oproj(const short* __restrict__ X,
                                             const short* __restrict__ WoT,
                                             float* __restrict__ out) {
  __shared__ short sA[2][128 * 32];
  __shared__ short sB[2][64 * 32];
  const int m0 = blockIdx.x * 128, n0 = blockIdx.y * 64;
  const int tid = threadIdx.x, wid = tid >> 6, lane = tid & 63;
  const int quad = lane >> 4, l16 = lane & 15;
  const int wr = wid >> 1, wc = wid & 1;

  auto stage = [&](int buf, int k0) {
#pragma unroll
    for (int i = 0; i < 2; ++i) {
      const int c = wid * 2 + i;
      const int ci = c * 64 + lane;
      load_lds16(X + (size_t)(m0 + (ci >> 2)) * DD + k0 + (ci & 3) * 8,
                 &sA[buf][c * 512]);
    }
    {
      const int ci = wid * 64 + lane;
      load_lds16(WoT + (size_t)(n0 + (ci >> 2)) * DD + k0 + (ci & 3) * 8,
                 &sB[buf][wid * 512]);
    }
  };

  floatx4 acc[4][2] = {};
  stage(0, 0);
  __syncthreads();
  int cur = 0;
  for (int k0 = 0; k0 < DD; k0 += 32) {
    if (k0 + 32 < DD) stage(cur ^ 1, k0 + 32);  // prefetch next K-step
    bf16x8 af[4], bfr[2];
#pragma unroll
    for (int mi = 0; mi < 4; ++mi)
      af[mi] = *(const bf16x8*)&sA[cur][(wr * 64 + mi * 16 + l16) * 32 +
                                        quad * 8];
#pragma unroll
    for (int ni = 0; ni < 2; ++ni)
      bfr[ni] = *(const bf16x8*)&sB[cur][(wc * 32 + ni * 16 + l16) * 32 +
                                         quad * 8];
#pragma unroll
    for (int mi = 0; mi < 4; ++mi)
#pragma unroll
      for (int ni = 0; ni < 2; ++ni)
        acc[mi][ni] = __builtin_amdgcn_mfma_f32_16x16x32_bf16(
            af[mi], bfr[ni], acc[mi][ni], 0, 0, 0);
    __syncthreads();
    cur ^= 1;
  }
#pragma unroll
  for (int mi = 0; mi < 4; ++mi)
#pragma unroll
    for (int ni = 0; ni < 2; ++ni)
#pragma unroll
      for (int r2 = 0; r2 < 4; ++r2)
        out[(size_t)(m0 + wr * 64 + mi * 16 + quad * 4 + r2) * DD + n0 +
            wc * 32 + ni * 16 + l16] = acc[mi][ni][r2];
}

// ---------------------------------------------------------------------------
extern "C" void kernel_launch(void* const* d_in, const int* in_sizes, int n_in,
                              void* d_out, int out_size, void* d_ws,
                              size_t ws_size, hipStream_t stream) {
  const float* q  = (const float*)d_in[0];
  const float* k  = (const float*)d_in[1];
  const float* v  = (const float*)d_in[2];
  const float* Wq = (const float*)d_in[3];
  const float* Wk = (const float*)d_in[4];
  const float* Wv = (const float*)d_in[5];
  const float* Wo = (const float*)d_in[6];
  const int* mask = (const int*)d_in[7];
  float* out = (float*)d_out;

  // workspace layout (shorts); X aliases qb (dead after proj). vhT has its
  // OWN region (kb is still live while proj writes vhT).
  short* ws = (short*)d_ws;
  const size_t NIN = (size_t)BB * SS * DD;  // 4,194,304
  const size_t NWH = (size_t)HH * HD * DD;  // 1,048,576
  short* qb  = ws;        // also X
  short* kb  = ws + NIN;
  short* vb  = ws + 2 * NIN;
  short* WqT = ws + 3 * NIN;
  short* WkT = WqT + NWH;
  short* WvT = WkT + NWH;
  short* WoT = WvT + NWH;
  short* qhp = WoT + (size_t)DD * DD;
  short* khp = qhp + NIN;
  short* vhT = khp + NIN;
  short* Xp  = qb;

  prep<<<dim3(13312), 256, 0, stream>>>(q, k, v, Wq, Wk, Wv, Wo, qb, kb, vb,
                                        WqT, WkT, WvT, WoT);
  proj<<<dim3(768), 256, 0, stream>>>(qb, kb, vb, WqT, WkT, WvT, mask, qhp,
                                      khp, vhT);
  attn<<<dim3(1024), 256, 0, stream>>>(qhp, khp, vhT, Xp);
  oproj<<<dim3(32, 16), 256, 0, stream>>>(Xp, WoT, out);
}

// Round 8
// 203.332 us; speedup vs baseline: 2.1006x; 1.0414x over previous
//
#include <hip/hip_runtime.h>
#include <hip/hip_bf16.h>

#define BB 2
#define SS 2048
#define DD 1024
#define HH 16
#define HD 64

typedef __attribute__((ext_vector_type(8))) short bf16x8;
typedef __attribute__((ext_vector_type(4))) float floatx4;

__device__ __forceinline__ short f2bf(float x) {
  __hip_bfloat16 h = __float2bfloat16(x);
  return __builtin_bit_cast(short, h);
}

// pack two fp32 -> two bf16 (RNE) in one instruction
__device__ __forceinline__ unsigned cvtpk_bf16(float lo, float hi) {
  unsigned r;
  asm("v_cvt_pk_bf16_f32 %0, %1, %2" : "=v"(r) : "v"(lo), "v"(hi));
  return r;
}

// async global->LDS, 16B per lane; LDS dest is wave-uniform base + lane*16
__device__ __forceinline__ void load_lds16(const void* g, void* l) {
  __builtin_amdgcn_global_load_lds(
      (const __attribute__((address_space(1))) unsigned int*)g,
      (__attribute__((address_space(3))) unsigned int*)l, 16, 0, 0);
}

__device__ __forceinline__ float redsum16(float v) {
  v += __shfl_xor(v, 1, 64);
  v += __shfl_xor(v, 2, 64);
  v += __shfl_xor(v, 4, 64);
  v += __shfl_xor(v, 8, 64);
  return v;
}

// ---------------------------------------------------------------------------
// prep: fused conv_in (q,k,v fp32->bf16) + conv_w (Wq/Wk/Wv transpose) +
// conv_wo (Wo transpose). 1D grid 13312, block 256.
// ---------------------------------------------------------------------------
__global__ __launch_bounds__(256) void prep(
    const float* __restrict__ q, const float* __restrict__ k,
    const float* __restrict__ v, const float* __restrict__ Wq,
    const float* __restrict__ Wk, const float* __restrict__ Wv,
    const float* __restrict__ Wo, short* __restrict__ qo,
    short* __restrict__ ko, short* __restrict__ vo, short* __restrict__ qT,
    short* __restrict__ kT, short* __restrict__ vT, short* __restrict__ WoT) {
  __shared__ short sT[64 * 72];
  const int blk = blockIdx.x;
  if (blk < 12288) {
    const int which = blk >> 12, x = blk & 4095;
    const float* src = which == 0 ? q : which == 1 ? k : v;
    short* dst       = which == 0 ? qo : which == 1 ? ko : vo;
    size_t i = ((size_t)x * 256 + threadIdx.x) * 4;
    float4 f = *(const float4*)(src + i);
    short4 s;
    s.x = f2bf(f.x); s.y = f2bf(f.y); s.z = f2bf(f.z); s.w = f2bf(f.w);
    *(short4*)(dst + i) = s;
    return;
  }
  const int t = threadIdx.x, r = t >> 2, c0 = (t & 3) * 16;
  const float* src;
  short* dst;
  if (blk < 13056) {  // conv_w: W[h][1024][64] -> WT[h*64+e][1024]
    const int b2 = blk - 12288, which = b2 >> 8, rr = b2 & 255;
    const int dtile = rr & 15, h = rr >> 4, d0 = dtile * 64;
    const float* W = which == 0 ? Wq : which == 1 ? Wk : Wv;
    short* WT      = which == 0 ? qT : which == 1 ? kT : vT;
    src = W + ((size_t)h * DD + d0 + r) * HD + c0;
    dst = WT + ((size_t)h * HD + r) * DD + d0 + c0;
  } else {  // conv_wo: Wo[1024][1024] -> WoT[n][k]
    const int b3 = blk - 13056;
    const int k0 = (b3 & 15) * 64, n0 = (b3 >> 4) * 64;
    src = Wo + (size_t)(k0 + r) * DD + n0 + c0;
    dst = WoT + (size_t)(n0 + r) * DD + k0 + c0;
  }
  const float4* s4 = (const float4*)src;
  float4 f0 = s4[0], f1 = s4[1], f2 = s4[2], f3 = s4[3];
  const float ff[16] = {f0.x, f0.y, f0.z, f0.w, f1.x, f1.y, f1.z, f1.w,
                        f2.x, f2.y, f2.z, f2.w, f3.x, f3.y, f3.z, f3.w};
#pragma unroll
  for (int j = 0; j < 16; ++j) sT[r * 72 + c0 + j] = f2bf(ff[j]);
  __syncthreads();
  alignas(16) short tmp[16];
#pragma unroll
  for (int j = 0; j < 16; ++j) tmp[j] = sT[(c0 + j) * 72 + r];
  *(int4*)(dst) = *(const int4*)(tmp);
  *(int4*)(dst + 8) = *(const int4*)(tmp + 8);
}

// ---------------------------------------------------------------------------
// Projection GEMM: ph = x @ W, M=4096, N=1024, K=1024. ROUND-8:
// (1) XOR slot-swizzle both sides: stage source slot (ci&3)^((ci>>3)&3)
//     (permutes within each 64B row -> coalescing preserved), fragment reads
//     use qs = quad^((l16>>1)&3) -> bank groups (4(l16&1)+qs)%8 cover all 8,
//     2 lanes each = conflict-free (was 3.2M conflict cycles).
// (2) T4 counted-vmcnt pipeline: TRIPLE-buffered staging, raw s_barrier +
//     s_waitcnt vmcnt(4) (4 loads/thread/stage; vmcnt(0) only last step),
//     stage k+2 issued after the barrier -> loads stay in flight ACROSS
//     barriers (no per-step drain). sched_barrier(0) pins ds_read order.
// LDS 48KB (3 bufs) + aliased v-transpose tr; grid 768 = 3 blocks/CU.
// q/k: masked rows ZEROED (score 0 -> exp2(0)=1 in attn), q scaled
// 1/8*log2(e). v: fused transpose -> vhT[bh][e][s]. XCD-decoded.
// ---------------------------------------------------------------------------
__global__ __launch_bounds__(256) void proj(
    const short* __restrict__ xq, const short* __restrict__ xk,
    const short* __restrict__ xv, const short* __restrict__ WqT,
    const short* __restrict__ WkT, const short* __restrict__ WvT,
    const int* __restrict__ mask, short* __restrict__ qh,
    short* __restrict__ kh, short* __restrict__ vhT) {
  __shared__ union {
    struct {
      short A[3][128 * 32];  // K-loop staging, triple-buffered
      short B[3][128 * 32];
    } s;
    short tr[64 * 136];  // v-transpose half-tile staging (aliases, post-loop)
  } u;
  const int xcd = blockIdx.x & 7, tt = blockIdx.x >> 3;
  const int which = tt >> 5;              // 0..2
  const int rest = tt & 31;
  const int j = ((xcd & 3) << 1) | (rest >> 4);   // n-block 0..7
  const int i = ((xcd >> 2) << 4) | (rest & 15);  // m-block 0..31
  const short* X  = which == 0 ? xq : which == 1 ? xk : xv;
  const short* WT = which == 0 ? WqT : which == 1 ? WkT : WvT;
  const int m0 = i * 128, n0 = j * 128;
  const int tid = threadIdx.x, wid = tid >> 6, lane = tid & 63;
  const int quad = lane >> 4, l16 = lane & 15;
  const int wr = wid >> 1, wc = wid & 1;

  auto stage = [&](int buf, int kk) {
#pragma unroll
    for (int ii = 0; ii < 2; ++ii) {
      const int c = wid * 2 + ii;
      const int ci = c * 64 + lane;
      const int srow = ci >> 2;
      const int sslot = (ci & 3) ^ ((ci >> 3) & 3);  // pre-swizzled source
      load_lds16(X + (size_t)(m0 + srow) * DD + kk + sslot * 8,
                 &u.s.A[buf][c * 512]);
      load_lds16(WT + (size_t)(n0 + srow) * DD + kk + sslot * 8,
                 &u.s.B[buf][c * 512]);
    }
  };

  floatx4 acc[4][4] = {};
  const int qs = (quad ^ ((l16 >> 1) & 3)) * 8;  // swizzled read slot
  stage(0, 0);
  stage(1, 32);
  int b0 = 0, b1 = 1, b2 = 2;
  for (int k0 = 0; k0 < DD; k0 += 32) {
    if (k0 + 32 < DD)
      asm volatile("s_waitcnt vmcnt(4)" ::: "memory");
    else
      asm volatile("s_waitcnt vmcnt(0)" ::: "memory");
    __builtin_amdgcn_s_barrier();
    __builtin_amdgcn_sched_barrier(0);
    if (k0 + 64 < DD) stage(b2, k0 + 64);
    bf16x8 af[4], bfr[4];
#pragma unroll
    for (int mi = 0; mi < 4; ++mi)
      af[mi] =
          *(const bf16x8*)&u.s.A[b0][(wr * 64 + mi * 16 + l16) * 32 + qs];
#pragma unroll
    for (int ni = 0; ni < 4; ++ni)
      bfr[ni] =
          *(const bf16x8*)&u.s.B[b0][(wc * 64 + ni * 16 + l16) * 32 + qs];
#pragma unroll
    for (int mi = 0; mi < 4; ++mi)
#pragma unroll
      for (int ni = 0; ni < 4; ++ni)
        acc[mi][ni] = __builtin_amdgcn_mfma_f32_16x16x32_bf16(
            af[mi], bfr[ni], acc[mi][ni], 0, 0, 0);
    const int t = b0; b0 = b1; b1 = b2; b2 = t;  // rotate buffers
  }

  if (which != 2) {
    short* dst = which == 0 ? qh : kh;
    // q: fold 1/sqrt(64) AND log2(e) (attn uses exp2). k: unit scale.
    const float scale = (which == 0) ? 0.18033688f : 1.0f;
#pragma unroll
    for (int mi = 0; mi < 4; ++mi)
#pragma unroll
      for (int r2 = 0; r2 < 4; ++r2) {
        const int m = m0 + wr * 64 + mi * 16 + quad * 4 + r2;
        const float rs = mask[m] ? 0.f : scale;  // zero masked rows
#pragma unroll
        for (int ni = 0; ni < 4; ++ni) {
          const int n = n0 + wc * 64 + ni * 16 + l16;
          dst[(size_t)m * DD + n] = f2bf(acc[mi][ni][r2] * rs);
        }
      }
  } else {
    // v: transpose 128x128 tile -> vhT[bh][e][s], two 64-row halves through
    // u.tr (aliases staging buffers — sync: K-loop reads must all be done)
    __syncthreads();
    const int b = m0 >> 11;
#pragma unroll
    for (int p = 0; p < 2; ++p) {
      if (wc == p) {  // waves holding nl in [p*64, p*64+64)
#pragma unroll
        for (int mi = 0; mi < 4; ++mi)
#pragma unroll
          for (int ni = 0; ni < 4; ++ni)
#pragma unroll
            for (int r2 = 0; r2 < 4; ++r2) {
              const int ml = wr * 64 + mi * 16 + quad * 4 + r2;  // s-local
              const int nl = ni * 16 + l16;  // (h,e)-local within half
              u.tr[nl * 136 + ml] = f2bf(acc[mi][ni][r2]);
            }
      }
      __syncthreads();
      const int row = tid >> 2, part = tid & 3;  // row 0..63, 32-short parts
      const int gn = n0 + p * 64 + row;
      const int h = gn >> 6, e = gn & 63;
      short* dstp = vhT + ((size_t)(b * HH + h) * HD + e) * SS + (m0 & 2047) +
                    part * 32;
      const short* srcl = &u.tr[row * 136 + part * 32];
#pragma unroll
      for (int jj = 0; jj < 4; ++jj)
        *(int4*)(dstp + jj * 8) = *(const int4*)(srcl + jj * 8);
      if (p == 0) __syncthreads();
    }
  }
}

// ---------------------------------------------------------------------------
// Flash attention, cooperative-LDS version (round-6, unchanged — 72->~35us).
// block = (bh, 64 q-rows), 4 waves x 16 rows; K/V tiles (64x64 bf16) staged
// into double-buffered LDS via global_load_lds, next tile staged BEFORE
// computing current; one __syncthreads per tile. G4 XOR swizzle on 16B slots
// applied both sides (pre-swizzled global source + swizzled read). No
// cross-wave combine. Diet softmax (pads pre-zeroed in proj, exp2, cvt_pk).
// 1024 blocks XCD-decoded, heavy-first.
// ---------------------------------------------------------------------------
__global__ __launch_bounds__(256, 2) void attn(
    const short* __restrict__ qh, const short* __restrict__ kh,
    const short* __restrict__ vhT, short* __restrict__ X) {
  // LDS shorts: [buf0: K 4096 | V 4096][buf1: K 4096 | V 4096][sP 4*1152]
  __shared__ short sm[16384 + 4 * 1152];
  const int tid = threadIdx.x, wid = tid >> 6, lane = tid & 63;
  const int quad = lane >> 4, l16 = lane & 15;
  const int xcd = blockIdx.x & 7, slot = blockIdx.x >> 3;  // 0..127
  const int bh = (xcd << 2) | (slot & 3);
  const int iblk = 31 - (slot >> 2);  // heavy blocks first per XCD
  const int nt = iblk + 1;            // causal extent in 64-col tiles
  const int b = bh >> 4, h = bh & 15;
  const int r0 = iblk * 64;
  const int wrow = r0 + wid * 16;  // this wave's first q-row

  const short* Q  = qh + (size_t)b * SS * DD + h * HD;
  const short* K  = kh + (size_t)b * SS * DD + h * HD;
  const short* Vt = vhT + (size_t)bh * HD * SS;
  short* sPw = &sm[16384 + wid * 1152];  // 16 rows x 72 shorts, per-wave
  const int swz = (l16 & 7) << 3;        // 16B-slot XOR swizzle, in shorts

  // staging geometry: chunk c in 0..511 covers K (row=c>>3, slot=c&7),
  // c in 512..1023 covers V likewise. Source slot pre-swizzled: slot^(row&7).
  const int sr0 = tid >> 3, ss0 = (tid & 7) ^ (sr0 & 7);          // rows 0..31
  const int sr1 = (tid + 256) >> 3, ss1 = (tid & 7) ^ (sr1 & 7);  // rows 32..63
  const short* pK0 = K + (size_t)sr0 * DD + ss0 * 8;
  const short* pK1 = K + (size_t)sr1 * DD + ss1 * 8;
  const short* pV0 = Vt + (size_t)sr0 * SS + ss0 * 8;
  const short* pV1 = Vt + (size_t)sr1 * SS + ss1 * 8;

  auto stage = [&](int buf, int t) {
    const size_t ko = (size_t)t * 64 * DD;
    const int tc = t * 64;
    short* base = &sm[buf * 8192];
    load_lds16(pK0 + ko, base + tid * 8);
    load_lds16(pK1 + ko, base + 2048 + tid * 8);
    load_lds16(pV0 + tc, base + 4096 + tid * 8);
    load_lds16(pV1 + tc, base + 6144 + tid * 8);
  };

  // Q fragments: A-layout, m = l16 (row wrow+l16), k = ks*32+quad*8
  bf16x8 aq[2];
#pragma unroll
  for (int ks = 0; ks < 2; ++ks)
    aq[ks] = *(const bf16x8*)(Q + (size_t)(wrow + l16) * DD + ks * 32 +
                              quad * 8);

  floatx4 o[4] = {};
  float lacc[4] = {};

  stage(0, 0);
  __syncthreads();
  int cur = 0;
  for (int t = 0; t < nt; ++t) {
    if (t + 1 < nt) stage(cur ^ 1, t + 1);  // prefetch next tile (no wait)
    const short* kb = &sm[cur * 8192];
    const short* vb = kb + 4096;
    // QK^T on the staged tile (swizzled reads)
    bf16x8 bk[4][2];
#pragma unroll
    for (int ni = 0; ni < 4; ++ni)
#pragma unroll
      for (int ks = 0; ks < 2; ++ks)
        bk[ni][ks] = *(const bf16x8*)&kb[(ni * 16 + l16) * 64 +
                                         ((ks * 32 + quad * 8) ^ swz)];
    floatx4 s[4] = {};
#pragma unroll
    for (int ks = 0; ks < 2; ++ks)
#pragma unroll
      for (int ni = 0; ni < 4; ++ni)
        s[ni] = __builtin_amdgcn_mfma_f32_16x16x32_bf16(aq[ks], bk[ni][ks],
                                                        s[ni], 0, 0, 0);
    const bool diag = (t == nt - 1);  // block-uniform
    const int t0 = t * 64;
#pragma unroll
    for (int ni = 0; ni < 4; ++ni)
#pragma unroll
      for (int r2p = 0; r2p < 2; ++r2p) {
        // pads pre-zeroed in proj -> s=0 -> exp2(0)=1 exactly
        float p0 = __builtin_amdgcn_exp2f(s[ni][2 * r2p]);
        float p1 = __builtin_amdgcn_exp2f(s[ni][2 * r2p + 1]);
        if (diag) {  // causal wins over pad
          const int row = wrow + quad * 4 + 2 * r2p;
          const int col = t0 + ni * 16 + l16;
          if (col > row) p0 = 0.f;
          if (col > row + 1) p1 = 0.f;
        }
        lacc[2 * r2p] += p0;
        lacc[2 * r2p + 1] += p1;
        const unsigned pk = cvtpk_bf16(p0, p1);
        short* wp = &sPw[(quad * 4 + 2 * r2p) * 72 + ni * 16 + l16];
        wp[0] = (short)pk;           // ds_write_b16
        wp[72] = (short)(pk >> 16);  // ds_write_b16_d16_hi
      }
    // O += P V : P via per-wave LDS round-trip; V from staged tile
#pragma unroll
    for (int ks = 0; ks < 2; ++ks) {
      const bf16x8 ap =
          *(const bf16x8*)&sPw[l16 * 72 + ks * 32 + quad * 8];
#pragma unroll
      for (int ei = 0; ei < 4; ++ei) {
        const bf16x8 bv = *(const bf16x8*)&vb[(ei * 16 + l16) * 64 +
                                              ((ks * 32 + quad * 8) ^ swz)];
        o[ei] = __builtin_amdgcn_mfma_f32_16x16x32_bf16(ap, bv, o[ei], 0, 0,
                                                        0);
      }
    }
    __syncthreads();  // next tile fully staged; all waves done with cur buf
    cur ^= 1;
  }

  // per-wave epilogue: denominator reduce over l16 group, scale, store
#pragma unroll
  for (int r2 = 0; r2 < 4; ++r2) {
    const float inv = 1.0f / redsum16(lacc[r2]);
    const int srow = wrow + quad * 4 + r2;
#pragma unroll
    for (int ei = 0; ei < 4; ++ei)
      X[((size_t)bh * SS + srow) * HD + ei * 16 + l16] =
          f2bf(o[ei][r2] * inv);
  }
}

// ---------------------------------------------------------------------------
// out = X[4096,1024] @ Wo, via WoT[n][k]. BM=128 BN=64 BK=32, 256 threads.
// grid (32, 16) = 512 blocks (2/CU). fp32 output. ROUND-8: same XOR slot
// swizzle + T4 counted-vmcnt triple-buffer as proj (3 loads/thread/stage
// -> vmcnt(3) steady, vmcnt(0) last).
// ---------------------------------------------------------------------------
__global__ __launch_bounds__(256) void oproj(const short* __restrict__ X,
                                             const short* __restrict__ WoT,
                                             float* __restrict__ out) {
  __shared__ short sA[3][128 * 32];
  __shared__ short sB[3][64 * 32];
  const int m0 = blockIdx.x * 128, n0 = blockIdx.y * 64;
  const int tid = threadIdx.x, wid = tid >> 6, lane = tid & 63;
  const int quad = lane >> 4, l16 = lane & 15;
  const int wr = wid >> 1, wc = wid & 1;

  auto stage = [&](int buf, int kk) {
#pragma unroll
    for (int i = 0; i < 2; ++i) {
      const int c = wid * 2 + i;
      const int ci = c * 64 + lane;
      const int srow = ci >> 2;
      const int sslot = (ci & 3) ^ ((ci >> 3) & 3);
      load_lds16(X + (size_t)(m0 + srow) * DD + kk + sslot * 8,
                 &sA[buf][c * 512]);
    }
    {
      const int ci = wid * 64 + lane;
      const int srow = ci >> 2;
      const int sslot = (ci & 3) ^ ((ci >> 3) & 3);
      load_lds16(WoT + (size_t)(n0 + srow) * DD + kk + sslot * 8,
                 &sB[buf][wid * 512]);
    }
  };

  floatx4 acc[4][2] = {};
  const int qs = (quad ^ ((l16 >> 1) & 3)) * 8;  // swizzled read slot
  stage(0, 0);
  stage(1, 32);
  int b0 = 0, b1 = 1, b2 = 2;
  for (int k0 = 0; k0 < DD; k0 += 32) {
    if (k0 + 32 < DD)
      asm volatile("s_waitcnt vmcnt(3)" ::: "memory");
    else
      asm volatile("s_waitcnt vmcnt(0)" ::: "memory");
    __builtin_amdgcn_s_barrier();
    __builtin_amdgcn_sched_barrier(0);
    if (k0 + 64 < DD) stage(b2, k0 + 64);
    bf16x8 af[4], bfr[2];
#pragma unroll
    for (int mi = 0; mi < 4; ++mi)
      af[mi] = *(const bf16x8*)&sA[b0][(wr * 64 + mi * 16 + l16) * 32 + qs];
#pragma unroll
    for (int ni = 0; ni < 2; ++ni)
      bfr[ni] = *(const bf16x8*)&sB[b0][(wc * 32 + ni * 16 + l16) * 32 + qs];
#pragma unroll
    for (int mi = 0; mi < 4; ++mi)
#pragma unroll
      for (int ni = 0; ni < 2; ++ni)
        acc[mi][ni] = __builtin_amdgcn_mfma_f32_16x16x32_bf16(
            af[mi], bfr[ni], acc[mi][ni], 0, 0, 0);
    const int t = b0; b0 = b1; b1 = b2; b2 = t;
  }
#pragma unroll
  for (int mi = 0; mi < 4; ++mi)
#pragma unroll
    for (int ni = 0; ni < 2; ++ni)
#pragma unroll
      for (int r2 = 0; r2 < 4; ++r2)
        out[(size_t)(m0 + wr * 64 + mi * 16 + quad * 4 + r2) * DD + n0 +
            wc * 32 + ni * 16 + l16] = acc[mi][ni][r2];
}

// ---------------------------------------------------------------------------
extern "C" void kernel_launch(void* const* d_in, const int* in_sizes, int n_in,
                              void* d_out, int out_size, void* d_ws,
                              size_t ws_size, hipStream_t stream) {
  const float* q  = (const float*)d_in[0];
  const float* k  = (const float*)d_in[1];
  const float* v  = (const float*)d_in[2];
  const float* Wq = (const float*)d_in[3];
  const float* Wk = (const float*)d_in[4];
  const float* Wv = (const float*)d_in[5];
  const float* Wo = (const float*)d_in[6];
  const int* mask = (const int*)d_in[7];
  float* out = (float*)d_out;

  // workspace layout (shorts); X aliases qb (dead after proj). vhT has its
  // OWN region (kb is still live while proj writes vhT).
  short* ws = (short*)d_ws;
  const size_t NIN = (size_t)BB * SS * DD;  // 4,194,304
  const size_t NWH = (size_t)HH * HD * DD;  // 1,048,576
  short* qb  = ws;        // also X
  short* kb  = ws + NIN;
  short* vb  = ws + 2 * NIN;
  short* WqT = ws + 3 * NIN;
  short* WkT = WqT + NWH;
  short* WvT = WkT + NWH;
  short* WoT = WvT + NWH;
  short* qhp = WoT + (size_t)DD * DD;
  short* khp = qhp + NIN;
  short* vhT = khp + NIN;
  short* Xp  = qb;

  prep<<<dim3(13312), 256, 0, stream>>>(q, k, v, Wq, Wk, Wv, Wo, qb, kb, vb,
                                        WqT, WkT, WvT, WoT);
  proj<<<dim3(768), 256, 0, stream>>>(qb, kb, vb, WqT, WkT, WvT, mask, qhp,
                                      khp, vhT);
  attn<<<dim3(1024), 256, 0, stream>>>(qhp, khp, vhT, Xp);
  oproj<<<dim3(32, 16), 256, 0, stream>>>(Xp, WoT, out);
}

// Round 10
// 201.717 us; speedup vs baseline: 2.1174x; 1.0080x over previous
//
#include <hip/hip_runtime.h>
#include <hip/hip_bf16.h>

#define BB 2
#define SS 2048
#define DD 1024
#define HH 16
#define HD 64

typedef __attribute__((ext_vector_type(8))) short bf16x8;
typedef __attribute__((ext_vector_type(4))) float floatx4;

__device__ __forceinline__ short f2bf(float x) {
  __hip_bfloat16 h = __float2bfloat16(x);
  return __builtin_bit_cast(short, h);
}

// pack two fp32 -> two bf16 (RNE) in one instruction
__device__ __forceinline__ unsigned cvtpk_bf16(float lo, float hi) {
  unsigned r;
  asm("v_cvt_pk_bf16_f32 %0, %1, %2" : "=v"(r) : "v"(lo), "v"(hi));
  return r;
}

// async global->LDS, 16B per lane; LDS dest is wave-uniform base + lane*16
__device__ __forceinline__ void load_lds16(const void* g, void* l) {
  __builtin_amdgcn_global_load_lds(
      (const __attribute__((address_space(1))) unsigned int*)g,
      (__attribute__((address_space(3))) unsigned int*)l, 16, 0, 0);
}

__device__ __forceinline__ float redsum16(float v) {
  v += __shfl_xor(v, 1, 64);
  v += __shfl_xor(v, 2, 64);
  v += __shfl_xor(v, 4, 64);
  v += __shfl_xor(v, 8, 64);
  return v;
}

// ---------------------------------------------------------------------------
// prep: fused conv_in (q,k,v fp32->bf16) + conv_w (Wq/Wk/Wv transpose) +
// conv_wo (Wo transpose). 1D grid 13312, block 256.
// ---------------------------------------------------------------------------
__global__ __launch_bounds__(256) void prep(
    const float* __restrict__ q, const float* __restrict__ k,
    const float* __restrict__ v, const float* __restrict__ Wq,
    const float* __restrict__ Wk, const float* __restrict__ Wv,
    const float* __restrict__ Wo, short* __restrict__ qo,
    short* __restrict__ ko, short* __restrict__ vo, short* __restrict__ qT,
    short* __restrict__ kT, short* __restrict__ vT, short* __restrict__ WoT) {
  __shared__ short sT[64 * 72];
  const int blk = blockIdx.x;
  if (blk < 12288) {
    const int which = blk >> 12, x = blk & 4095;
    const float* src = which == 0 ? q : which == 1 ? k : v;
    short* dst       = which == 0 ? qo : which == 1 ? ko : vo;
    size_t i = ((size_t)x * 256 + threadIdx.x) * 4;
    float4 f = *(const float4*)(src + i);
    short4 s;
    s.x = f2bf(f.x); s.y = f2bf(f.y); s.z = f2bf(f.z); s.w = f2bf(f.w);
    *(short4*)(dst + i) = s;
    return;
  }
  const int t = threadIdx.x, r = t >> 2, c0 = (t & 3) * 16;
  const float* src;
  short* dst;
  if (blk < 13056) {  // conv_w: W[h][1024][64] -> WT[h*64+e][1024]
    const int b2 = blk - 12288, which = b2 >> 8, rr = b2 & 255;
    const int dtile = rr & 15, h = rr >> 4, d0 = dtile * 64;
    const float* W = which == 0 ? Wq : which == 1 ? Wk : Wv;
    short* WT      = which == 0 ? qT : which == 1 ? kT : vT;
    src = W + ((size_t)h * DD + d0 + r) * HD + c0;
    dst = WT + ((size_t)h * HD + r) * DD + d0 + c0;
  } else {  // conv_wo: Wo[1024][1024] -> WoT[n][k]
    const int b3 = blk - 13056;
    const int k0 = (b3 & 15) * 64, n0 = (b3 >> 4) * 64;
    src = Wo + (size_t)(k0 + r) * DD + n0 + c0;
    dst = WoT + (size_t)(n0 + r) * DD + k0 + c0;
  }
  const float4* s4 = (const float4*)src;
  float4 f0 = s4[0], f1 = s4[1], f2 = s4[2], f3 = s4[3];
  const float ff[16] = {f0.x, f0.y, f0.z, f0.w, f1.x, f1.y, f1.z, f1.w,
                        f2.x, f2.y, f2.z, f2.w, f3.x, f3.y, f3.z, f3.w};
#pragma unroll
  for (int j = 0; j < 16; ++j) sT[r * 72 + c0 + j] = f2bf(ff[j]);
  __syncthreads();
  alignas(16) short tmp[16];
#pragma unroll
  for (int j = 0; j < 16; ++j) tmp[j] = sT[(c0 + j) * 72 + r];
  *(int4*)(dst) = *(const int4*)(tmp);
  *(int4*)(dst + 8) = *(const int4*)(tmp + 8);
}

// ---------------------------------------------------------------------------
// Projection GEMM: ph = x @ W, M=4096, N=1024, K=1024. ROUND-8 verified:
// XOR slot-swizzle both sides (bank-conflict-free, 3.2M->65K) + T4
// counted-vmcnt triple-buffer pipeline. ROUND-10: j (n-block) is the fast
// index — pure bit-permutation of the block decode (provably bijective),
// gives the X panel back-to-back reuse across its 2 j's. NO setprio
// (round-9's only semantically-plausible failure culprit — dropped).
// LDS 48KB (3 bufs) + aliased v-transpose tr; grid 768 = 3 blocks/CU.
// q/k: masked rows ZEROED (score 0 -> exp2(0)=1 in attn), q scaled
// 1/8*log2(e). v: fused transpose -> vhT[bh][e][s]. XCD-decoded.
// ---------------------------------------------------------------------------
__global__ __launch_bounds__(256) void proj(
    const short* __restrict__ xq, const short* __restrict__ xk,
    const short* __restrict__ xv, const short* __restrict__ WqT,
    const short* __restrict__ WkT, const short* __restrict__ WvT,
    const int* __restrict__ mask, short* __restrict__ qh,
    short* __restrict__ kh, short* __restrict__ vhT) {
  __shared__ union {
    struct {
      short A[3][128 * 32];  // K-loop staging, triple-buffered
      short B[3][128 * 32];
    } s;
    short tr[64 * 136];  // v-transpose half-tile staging (aliases, post-loop)
  } u;
  const int xcd = blockIdx.x & 7, tt = blockIdx.x >> 3;
  const int which = tt >> 5;              // 0..2
  const int rest = tt & 31;
  const int j = ((xcd & 3) << 1) | (rest & 1);    // n-block 0..7 (fast)
  const int i = ((xcd >> 2) << 4) | (rest >> 1);  // m-block 0..31
  const short* X  = which == 0 ? xq : which == 1 ? xk : xv;
  const short* WT = which == 0 ? WqT : which == 1 ? WkT : WvT;
  const int m0 = i * 128, n0 = j * 128;
  const int tid = threadIdx.x, wid = tid >> 6, lane = tid & 63;
  const int quad = lane >> 4, l16 = lane & 15;
  const int wr = wid >> 1, wc = wid & 1;

  auto stage = [&](int buf, int kk) {
#pragma unroll
    for (int ii = 0; ii < 2; ++ii) {
      const int c = wid * 2 + ii;
      const int ci = c * 64 + lane;
      const int srow = ci >> 2;
      const int sslot = (ci & 3) ^ ((ci >> 3) & 3);  // pre-swizzled source
      load_lds16(X + (size_t)(m0 + srow) * DD + kk + sslot * 8,
                 &u.s.A[buf][c * 512]);
      load_lds16(WT + (size_t)(n0 + srow) * DD + kk + sslot * 8,
                 &u.s.B[buf][c * 512]);
    }
  };

  floatx4 acc[4][4] = {};
  const int qs = (quad ^ ((l16 >> 1) & 3)) * 8;  // swizzled read slot
  stage(0, 0);
  stage(1, 32);
  int b0 = 0, b1 = 1, b2 = 2;
  for (int k0 = 0; k0 < DD; k0 += 32) {
    if (k0 + 32 < DD)
      asm volatile("s_waitcnt vmcnt(4)" ::: "memory");
    else
      asm volatile("s_waitcnt vmcnt(0)" ::: "memory");
    __builtin_amdgcn_s_barrier();
    __builtin_amdgcn_sched_barrier(0);
    if (k0 + 64 < DD) stage(b2, k0 + 64);
    bf16x8 af[4], bfr[4];
#pragma unroll
    for (int mi = 0; mi < 4; ++mi)
      af[mi] =
          *(const bf16x8*)&u.s.A[b0][(wr * 64 + mi * 16 + l16) * 32 + qs];
#pragma unroll
    for (int ni = 0; ni < 4; ++ni)
      bfr[ni] =
          *(const bf16x8*)&u.s.B[b0][(wc * 64 + ni * 16 + l16) * 32 + qs];
#pragma unroll
    for (int mi = 0; mi < 4; ++mi)
#pragma unroll
      for (int ni = 0; ni < 4; ++ni)
        acc[mi][ni] = __builtin_amdgcn_mfma_f32_16x16x32_bf16(
            af[mi], bfr[ni], acc[mi][ni], 0, 0, 0);
    const int t = b0; b0 = b1; b1 = b2; b2 = t;  // rotate buffers
  }

  if (which != 2) {
    short* dst = which == 0 ? qh : kh;
    // q: fold 1/sqrt(64) AND log2(e) (attn uses exp2). k: unit scale.
    const float scale = (which == 0) ? 0.18033688f : 1.0f;
#pragma unroll
    for (int mi = 0; mi < 4; ++mi)
#pragma unroll
      for (int r2 = 0; r2 < 4; ++r2) {
        const int m = m0 + wr * 64 + mi * 16 + quad * 4 + r2;
        const float rs = mask[m] ? 0.f : scale;  // zero masked rows
#pragma unroll
        for (int ni = 0; ni < 4; ++ni) {
          const int n = n0 + wc * 64 + ni * 16 + l16;
          dst[(size_t)m * DD + n] = f2bf(acc[mi][ni][r2] * rs);
        }
      }
  } else {
    // v: transpose 128x128 tile -> vhT[bh][e][s], two 64-row halves through
    // u.tr (aliases staging buffers — sync: K-loop reads must all be done)
    __syncthreads();
    const int b = m0 >> 11;
#pragma unroll
    for (int p = 0; p < 2; ++p) {
      if (wc == p) {  // waves holding nl in [p*64, p*64+64)
#pragma unroll
        for (int mi = 0; mi < 4; ++mi)
#pragma unroll
          for (int ni = 0; ni < 4; ++ni)
#pragma unroll
            for (int r2 = 0; r2 < 4; ++r2) {
              const int ml = wr * 64 + mi * 16 + quad * 4 + r2;  // s-local
              const int nl = ni * 16 + l16;  // (h,e)-local within half
              u.tr[nl * 136 + ml] = f2bf(acc[mi][ni][r2]);
            }
      }
      __syncthreads();
      const int row = tid >> 2, part = tid & 3;  // row 0..63, 32-short parts
      const int gn = n0 + p * 64 + row;
      const int h = gn >> 6, e = gn & 63;
      short* dstp = vhT + ((size_t)(b * HH + h) * HD + e) * SS + (m0 & 2047) +
                    part * 32;
      const short* srcl = &u.tr[row * 136 + part * 32];
#pragma unroll
      for (int jj = 0; jj < 4; ++jj)
        *(int4*)(dstp + jj * 8) = *(const int4*)(srcl + jj * 8);
      if (p == 0) __syncthreads();
    }
  }
}

// ---------------------------------------------------------------------------
// Flash attention, cooperative-LDS version — EXACT round-6/7/8 body (passed
// 3 consecutive rounds, ~35us). NO setprio (round-9 suspect, removed).
// block = (bh, 64 q-rows), 4 waves x 16 rows; K/V tiles (64x64 bf16) staged
// into double-buffered LDS via global_load_lds, next tile staged BEFORE
// computing current; one __syncthreads per tile. G4 XOR swizzle on 16B slots
// applied both sides. No cross-wave combine. Diet softmax (pads pre-zeroed
// in proj, exp2, cvt_pk). 1024 blocks XCD-decoded, heavy-first.
// ---------------------------------------------------------------------------
__global__ __launch_bounds__(256, 2) void attn(
    const short* __restrict__ qh, const short* __restrict__ kh,
    const short* __restrict__ vhT, short* __restrict__ X) {
  // LDS shorts: [buf0: K 4096 | V 4096][buf1: K 4096 | V 4096][sP 4*1152]
  __shared__ short sm[16384 + 4 * 1152];
  const int tid = threadIdx.x, wid = tid >> 6, lane = tid & 63;
  const int quad = lane >> 4, l16 = lane & 15;
  const int xcd = blockIdx.x & 7, slot = blockIdx.x >> 3;  // 0..127
  const int bh = (xcd << 2) | (slot & 3);
  const int iblk = 31 - (slot >> 2);  // heavy blocks first per XCD
  const int nt = iblk + 1;            // causal extent in 64-col tiles
  const int b = bh >> 4, h = bh & 15;
  const int r0 = iblk * 64;
  const int wrow = r0 + wid * 16;  // this wave's first q-row

  const short* Q  = qh + (size_t)b * SS * DD + h * HD;
  const short* K  = kh + (size_t)b * SS * DD + h * HD;
  const short* Vt = vhT + (size_t)bh * HD * SS;
  short* sPw = &sm[16384 + wid * 1152];  // 16 rows x 72 shorts, per-wave
  const int swz = (l16 & 7) << 3;        // 16B-slot XOR swizzle, in shorts

  // staging geometry: chunk c in 0..511 covers K (row=c>>3, slot=c&7),
  // c in 512..1023 covers V likewise. Source slot pre-swizzled: slot^(row&7).
  const int sr0 = tid >> 3, ss0 = (tid & 7) ^ (sr0 & 7);          // rows 0..31
  const int sr1 = (tid + 256) >> 3, ss1 = (tid & 7) ^ (sr1 & 7);  // rows 32..63
  const short* pK0 = K + (size_t)sr0 * DD + ss0 * 8;
  const short* pK1 = K + (size_t)sr1 * DD + ss1 * 8;
  const short* pV0 = Vt + (size_t)sr0 * SS + ss0 * 8;
  const short* pV1 = Vt + (size_t)sr1 * SS + ss1 * 8;

  auto stage = [&](int buf, int t) {
    const size_t ko = (size_t)t * 64 * DD;
    const int tc = t * 64;
    short* base = &sm[buf * 8192];
    load_lds16(pK0 + ko, base + tid * 8);
    load_lds16(pK1 + ko, base + 2048 + tid * 8);
    load_lds16(pV0 + tc, base + 4096 + tid * 8);
    load_lds16(pV1 + tc, base + 6144 + tid * 8);
  };

  // Q fragments: A-layout, m = l16 (row wrow+l16), k = ks*32+quad*8
  bf16x8 aq[2];
#pragma unroll
  for (int ks = 0; ks < 2; ++ks)
    aq[ks] = *(const bf16x8*)(Q + (size_t)(wrow + l16) * DD + ks * 32 +
                              quad * 8);

  floatx4 o[4] = {};
  float lacc[4] = {};

  stage(0, 0);
  __syncthreads();
  int cur = 0;
  for (int t = 0; t < nt; ++t) {
    if (t + 1 < nt) stage(cur ^ 1, t + 1);  // prefetch next tile (no wait)
    const short* kb = &sm[cur * 8192];
    const short* vb = kb + 4096;
    // QK^T on the staged tile (swizzled reads)
    bf16x8 bk[4][2];
#pragma unroll
    for (int ni = 0; ni < 4; ++ni)
#pragma unroll
      for (int ks = 0; ks < 2; ++ks)
        bk[ni][ks] = *(const bf16x8*)&kb[(ni * 16 + l16) * 64 +
                                         ((ks * 32 + quad * 8) ^ swz)];
    floatx4 s[4] = {};
#pragma unroll
    for (int ks = 0; ks < 2; ++ks)
#pragma unroll
      for (int ni = 0; ni < 4; ++ni)
        s[ni] = __builtin_amdgcn_mfma_f32_16x16x32_bf16(aq[ks], bk[ni][ks],
                                                        s[ni], 0, 0, 0);
    const bool diag = (t == nt - 1);  // block-uniform
    const int t0 = t * 64;
#pragma unroll
    for (int ni = 0; ni < 4; ++ni)
#pragma unroll
      for (int r2p = 0; r2p < 2; ++r2p) {
        // pads pre-zeroed in proj -> s=0 -> exp2(0)=1 exactly
        float p0 = __builtin_amdgcn_exp2f(s[ni][2 * r2p]);
        float p1 = __builtin_amdgcn_exp2f(s[ni][2 * r2p + 1]);
        if (diag) {  // causal wins over pad
          const int row = wrow + quad * 4 + 2 * r2p;
          const int col = t0 + ni * 16 + l16;
          if (col > row) p0 = 0.f;
          if (col > row + 1) p1 = 0.f;
        }
        lacc[2 * r2p] += p0;
        lacc[2 * r2p + 1] += p1;
        const unsigned pk = cvtpk_bf16(p0, p1);
        short* wp = &sPw[(quad * 4 + 2 * r2p) * 72 + ni * 16 + l16];
        wp[0] = (short)pk;           // ds_write_b16
        wp[72] = (short)(pk >> 16);  // ds_write_b16_d16_hi
      }
    // O += P V : P via per-wave LDS round-trip; V from staged tile
#pragma unroll
    for (int ks = 0; ks < 2; ++ks) {
      const bf16x8 ap =
          *(const bf16x8*)&sPw[l16 * 72 + ks * 32 + quad * 8];
#pragma unroll
      for (int ei = 0; ei < 4; ++ei) {
        const bf16x8 bv = *(const bf16x8*)&vb[(ei * 16 + l16) * 64 +
                                              ((ks * 32 + quad * 8) ^ swz)];
        o[ei] = __builtin_amdgcn_mfma_f32_16x16x32_bf16(ap, bv, o[ei], 0, 0,
                                                        0);
      }
    }
    __syncthreads();  // next tile fully staged; all waves done with cur buf
    cur ^= 1;
  }

  // per-wave epilogue: denominator reduce over l16 group, scale, store
#pragma unroll
  for (int r2 = 0; r2 < 4; ++r2) {
    const float inv = 1.0f / redsum16(lacc[r2]);
    const int srow = wrow + quad * 4 + r2;
#pragma unroll
    for (int ei = 0; ei < 4; ++ei)
      X[((size_t)bh * SS + srow) * HD + ei * 16 + l16] =
          f2bf(o[ei][r2] * inv);
  }
}

// ---------------------------------------------------------------------------
// out = X[4096,1024] @ Wo, via WoT[n][k]. BM=128 BN=64 BK=32, 256 threads.
// ROUND-10: 1D grid 512, XCD-decoded (bit-permutation, provably bijective) —
// each XCD owns 4 m-panels x all 16 n-blocks (X 1MB + WoT 2MB = 3MB <= 4MB
// L2 -> staging L2-resident after first touch; previously every XCD streamed
// all 10.4MB). Keeps round-8 XOR slot swizzle + T4 counted-vmcnt triple
// buffer (vmcnt(3) steady).
// ---------------------------------------------------------------------------
__global__ __launch_bounds__(256) void oproj(const short* __restrict__ X,
                                             const short* __restrict__ WoT,
                                             float* __restrict__ out) {
  __shared__ short sA[3][128 * 32];
  __shared__ short sB[3][64 * 32];
  const int blk = blockIdx.x;
  const int xcd = blk & 7, r = blk >> 3;          // r 0..63
  const int n0 = (r >> 2) * 64;                   // n-block 0..15 (slow)
  const int m0 = ((xcd << 2) | (r & 3)) * 128;    // m-block: XCD quad + fast
  const int tid = threadIdx.x, wid = tid >> 6, lane = tid & 63;
  const int quad = lane >> 4, l16 = lane & 15;
  const int wr = wid >> 1, wc = wid & 1;

  auto stage = [&](int buf, int kk) {
#pragma unroll
    for (int i = 0; i < 2; ++i) {
      const int c = wid * 2 + i;
      const int ci = c * 64 + lane;
      const int srow = ci >> 2;
      const int sslot = (ci & 3) ^ ((ci >> 3) & 3);
      load_lds16(X + (size_t)(m0 + srow) * DD + kk + sslot * 8,
                 &sA[buf][c * 512]);
    }
    {
      const int ci = wid * 64 + lane;
      const int srow = ci >> 2;
      const int sslot = (ci & 3) ^ ((ci >> 3) & 3);
      load_lds16(WoT + (size_t)(n0 + srow) * DD + kk + sslot * 8,
                 &sB[buf][wid * 512]);
    }
  };

  floatx4 acc[4][2] = {};
  const int qs = (quad ^ ((l16 >> 1) & 3)) * 8;  // swizzled read slot
  stage(0, 0);
  stage(1, 32);
  int b0 = 0, b1 = 1, b2 = 2;
  for (int k0 = 0; k0 < DD; k0 += 32) {
    if (k0 + 32 < DD)
      asm volatile("s_waitcnt vmcnt(3)" ::: "memory");
    else
      asm volatile("s_waitcnt vmcnt(0)" ::: "memory");
    __builtin_amdgcn_s_barrier();
    __builtin_amdgcn_sched_barrier(0);
    if (k0 + 64 < DD) stage(b2, k0 + 64);
    bf16x8 af[4], bfr[2];
#pragma unroll
    for (int mi = 0; mi < 4; ++mi)
      af[mi] = *(const bf16x8*)&sA[b0][(wr * 64 + mi * 16 + l16) * 32 + qs];
#pragma unroll
    for (int ni = 0; ni < 2; ++ni)
      bfr[ni] = *(const bf16x8*)&sB[b0][(wc * 32 + ni * 16 + l16) * 32 + qs];
#pragma unroll
    for (int mi = 0; mi < 4; ++mi)
#pragma unroll
      for (int ni = 0; ni < 2; ++ni)
        acc[mi][ni] = __builtin_amdgcn_mfma_f32_16x16x32_bf16(
            af[mi], bfr[ni], acc[mi][ni], 0, 0, 0);
    const int t = b0; b0 = b1; b1 = b2; b2 = t;
  }
#pragma unroll
  for (int mi = 0; mi < 4; ++mi)
#pragma unroll
    for (int ni = 0; ni < 2; ++ni)
#pragma unroll
      for (int r2 = 0; r2 < 4; ++r2)
        out[(size_t)(m0 + wr * 64 + mi * 16 + quad * 4 + r2) * DD + n0 +
            wc * 32 + ni * 16 + l16] = acc[mi][ni][r2];
}

// ---------------------------------------------------------------------------
extern "C" void kernel_launch(void* const* d_in, const int* in_sizes, int n_in,
                              void* d_out, int out_size, void* d_ws,
                              size_t ws_size, hipStream_t stream) {
  const float* q  = (const float*)d_in[0];
  const float* k  = (const float*)d_in[1];
  const float* v  = (const float*)d_in[2];
  const float* Wq = (const float*)d_in[3];
  const float* Wk = (const float*)d_in[4];
  const float* Wv = (const float*)d_in[5];
  const float* Wo = (const float*)d_in[6];
  const int* mask = (const int*)d_in[7];
  float* out = (float*)d_out;

  // workspace layout (shorts); X aliases qb (dead after proj). vhT has its
  // OWN region (kb is still live while proj writes vhT).
  short* ws = (short*)d_ws;
  const size_t NIN = (size_t)BB * SS * DD;  // 4,194,304
  const size_t NWH = (size_t)HH * HD * DD;  // 1,048,576
  short* qb  = ws;        // also X
  short* kb  = ws + NIN;
  short* vb  = ws + 2 * NIN;
  short* WqT = ws + 3 * NIN;
  short* WkT = WqT + NWH;
  short* WvT = WkT + NWH;
  short* WoT = WvT + NWH;
  short* qhp = WoT + (size_t)DD * DD;
  short* khp = qhp + NIN;
  short* vhT = khp + NIN;
  short* Xp  = qb;

  prep<<<dim3(13312), 256, 0, stream>>>(q, k, v, Wq, Wk, Wv, Wo, qb, kb, vb,
                                        WqT, WkT, WvT, WoT);
  proj<<<dim3(768), 256, 0, stream>>>(qb, kb, vb, WqT, WkT, WvT, mask, qhp,
                                      khp, vhT);
  attn<<<dim3(1024), 256, 0, stream>>>(qhp, khp, vhT, Xp);
  oproj<<<dim3(512), 256, 0, stream>>>(Xp, WoT, out);
}